// Round 1
// baseline (332.343 us; speedup 1.0000x reference)
//
#include <hip/hip_runtime.h>
#include <hip/hip_bf16.h>

#define H 2048
#define K 1024
#define R 3
#define BB 8
#define S 2048

typedef __bf16 bf16x8 __attribute__((ext_vector_type(8)));
typedef float f32x4 __attribute__((ext_vector_type(4)));
typedef unsigned short ushort8 __attribute__((ext_vector_type(8)));

static __device__ __forceinline__ unsigned short f2bf(float f) {
    unsigned int u = __float_as_uint(f);
    u += 0x7FFFu + ((u >> 16) & 1u);   // round-to-nearest-even
    return (unsigned short)(u >> 16);
}

#define GLOAD_LDS16(g, l)                                                      \
    __builtin_amdgcn_global_load_lds(                                          \
        (const __attribute__((address_space(1))) void*)(g),                    \
        (__attribute__((address_space(3))) void*)(l), 16, 0, 0)

// ---------------- convert hidden f32 -> bf16 ----------------
__global__ __launch_bounds__(256) void cvt_hs(const float* __restrict__ in,
                                              unsigned short* __restrict__ out,
                                              int n8) {
    int stride = gridDim.x * blockDim.x;
    for (int i = blockIdx.x * blockDim.x + threadIdx.x; i < n8; i += stride) {
        const float4* p = (const float4*)(in + (size_t)i * 8);
        float4 a = p[0], b = p[1];
        union { unsigned short us[8]; ushort8 v; } o;
        o.us[0] = f2bf(a.x); o.us[1] = f2bf(a.y);
        o.us[2] = f2bf(a.z); o.us[3] = f2bf(a.w);
        o.us[4] = f2bf(b.x); o.us[5] = f2bf(b.y);
        o.us[6] = f2bf(b.z); o.us[7] = f2bf(b.w);
        *(ushort8*)(out + (size_t)i * 8) = o.v;
    }
}

// -------- transpose+convert: in f32 [rows][cols] -> out bf16 [cols][rows] ----
__global__ __launch_bounds__(256) void tpose(const float* __restrict__ in,
                                             unsigned short* __restrict__ out,
                                             int rows, int cols) {
    __shared__ float tile[32][33];
    int rr = blockIdx.z;
    const float* ip = in + (size_t)rr * rows * cols;
    unsigned short* op = out + (size_t)rr * rows * cols;
    int x = blockIdx.x * 32 + threadIdx.x;    // input col
    int y0 = blockIdx.y * 32 + threadIdx.y;   // input row
#pragma unroll
    for (int j = 0; j < 32; j += 8)
        tile[threadIdx.y + j][threadIdx.x] = ip[(size_t)(y0 + j) * cols + x];
    __syncthreads();
    int ox = blockIdx.y * 32 + threadIdx.x;   // output col = input row
    int oy0 = blockIdx.x * 32 + threadIdx.y;  // output row = input col
#pragma unroll
    for (int j = 0; j < 32; j += 8)
        op[(size_t)(oy0 + j) * rows + ox] = f2bf(tile[threadIdx.x][threadIdx.y + j]);
}

// ---------------- NT GEMM, m97 structure: 128x128 tile, BK=32 ----------------
// A: bf16 [BB*S][KC] row-major (per-batch segment). Bt: bf16 [R][N][KC].
// EPI 0: out = bf16 gelu(acc + bias)   -> h_ws [BB*S][N]
// EPI 1: out = f32  acc + bias + resid -> d_out [BB*S][N]
template <int KC, int EPI>
__global__ __launch_bounds__(256, 2) void gemm_nt(
    const unsigned short* __restrict__ A, const unsigned short* __restrict__ Bt,
    const int* __restrict__ role, const float* __restrict__ bias,
    const float* __restrict__ resid, void* __restrict__ Out, int N) {
    __shared__ char smem[16384];
    char* sA = smem;
    char* sB = smem + 8192;
    const int tid = threadIdx.x;
    const int wid = tid >> 6, lane = tid & 63;
    const int wm = wid >> 1, wn = wid & 1;
    const int lr = lane & 15, lc = lane >> 4;
    const int z = blockIdx.z;
    const int r = role[z];
    const int tm = blockIdx.y, tn = blockIdx.x;

    const size_t arow0 = (size_t)z * S + (size_t)tm * 128;
    const unsigned short* Ab = A + arow0 * KC;
    const unsigned short* Bb = Bt + ((size_t)r * N + (size_t)tn * 128) * KC;

    f32x4 acc[4][4] = {};

    const int idx0 = tid * 16;            // byte offset in a 4096B round
    const int r0 = idx0 >> 6;             // row (64B = 32 bf16 per row)
    const int cb = idx0 & 63;             // byte within row

    for (int kt = 0; kt < KC; kt += 32) {
        const char* ga0 = (const char*)Ab + (size_t)r0 * (KC * 2) + (size_t)kt * 2 + cb;
        const char* ga1 = ga0 + (size_t)64 * (KC * 2);
        const char* gb0 = (const char*)Bb + (size_t)r0 * (KC * 2) + (size_t)kt * 2 + cb;
        const char* gb1 = gb0 + (size_t)64 * (KC * 2);
        GLOAD_LDS16(ga0, sA + idx0);
        GLOAD_LDS16(ga1, sA + 4096 + idx0);
        GLOAD_LDS16(gb0, sB + idx0);
        GLOAD_LDS16(gb1, sB + 4096 + idx0);
        __syncthreads();

        bf16x8 a[4], b[4];
#pragma unroll
        for (int i = 0; i < 4; i++)
            a[i] = *(const bf16x8*)(sA + ((wm * 64 + i * 16 + lr) * 64 + lc * 16));
#pragma unroll
        for (int i = 0; i < 4; i++)
            b[i] = *(const bf16x8*)(sB + ((wn * 64 + i * 16 + lr) * 64 + lc * 16));
#pragma unroll
        for (int i = 0; i < 4; i++)
#pragma unroll
            for (int j = 0; j < 4; j++)
                acc[i][j] = __builtin_amdgcn_mfma_f32_16x16x32_bf16(a[i], b[j], acc[i][j], 0, 0, 0);
        __syncthreads();
    }

    const int base_m = tm * 128 + wm * 64;
    const int base_n = tn * 128 + wn * 64;
    float bn[4];
    const float* bp = bias + (size_t)r * N + base_n;
#pragma unroll
    for (int j = 0; j < 4; j++) bn[j] = bp[j * 16 + lr];

    if (EPI == 0) {
        unsigned short* o = (unsigned short*)Out;
#pragma unroll
        for (int i = 0; i < 4; i++) {
#pragma unroll
            for (int j = 0; j < 4; j++) {
#pragma unroll
                for (int q = 0; q < 4; q++) {
                    size_t grow = (size_t)z * S + base_m + i * 16 + lc * 4 + q;
                    int col = base_n + j * 16 + lr;
                    float x = acc[i][j][q] + bn[j];
                    float g = 0.5f * x * (1.0f + erff(x * 0.70710678118654752f));
                    o[grow * N + col] = f2bf(g);
                }
            }
        }
    } else {
        float* o = (float*)Out;
#pragma unroll
        for (int i = 0; i < 4; i++) {
#pragma unroll
            for (int j = 0; j < 4; j++) {
#pragma unroll
                for (int q = 0; q < 4; q++) {
                    size_t grow = (size_t)z * S + base_m + i * 16 + lc * 4 + q;
                    int col = base_n + j * 16 + lr;
                    float y = acc[i][j][q] + bn[j] + resid[grow * H + col];
                    o[grow * (size_t)N + col] = y;
                }
            }
        }
    }
}

// ---------------- LayerNorm in place on d_out ----------------
__global__ __launch_bounds__(256) void ln_k(float* __restrict__ y,
                                            const int* __restrict__ role,
                                            const float* __restrict__ gamma,
                                            const float* __restrict__ beta) {
    int row = blockIdx.x;       // 0..BB*S-1
    int z = row / S;
    int r = role[z];
    float* yp = y + (size_t)row * H;
    int t = threadIdx.x;
    float4 v0 = ((const float4*)yp)[t];
    float4 v1 = ((const float4*)yp)[t + 256];
    float s = v0.x + v0.y + v0.z + v0.w + v1.x + v1.y + v1.z + v1.w;
    float ss = v0.x * v0.x + v0.y * v0.y + v0.z * v0.z + v0.w * v0.w +
               v1.x * v1.x + v1.y * v1.y + v1.z * v1.z + v1.w * v1.w;
#pragma unroll
    for (int o = 32; o; o >>= 1) {
        s += __shfl_down(s, o);
        ss += __shfl_down(ss, o);
    }
    __shared__ float ws_s[4], ws_ss[4];
    int wid = t >> 6, lane = t & 63;
    if (lane == 0) { ws_s[wid] = s; ws_ss[wid] = ss; }
    __syncthreads();
    s = ws_s[0] + ws_s[1] + ws_s[2] + ws_s[3];
    ss = ws_ss[0] + ws_ss[1] + ws_ss[2] + ws_ss[3];
    float mean = s * (1.0f / H);
    float var = ss * (1.0f / H) - mean * mean;
    float rstd = rsqrtf(var + 1e-5f);
    const float4* gp = (const float4*)(gamma + (size_t)r * H);
    const float4* bpv = (const float4*)(beta + (size_t)r * H);
    float4 g0 = gp[t], g1 = gp[t + 256];
    float4 b0 = bpv[t], b1 = bpv[t + 256];
    float4 o0, o1;
    o0.x = (v0.x - mean) * rstd * g0.x + b0.x;
    o0.y = (v0.y - mean) * rstd * g0.y + b0.y;
    o0.z = (v0.z - mean) * rstd * g0.z + b0.z;
    o0.w = (v0.w - mean) * rstd * g0.w + b0.w;
    o1.x = (v1.x - mean) * rstd * g1.x + b1.x;
    o1.y = (v1.y - mean) * rstd * g1.y + b1.y;
    o1.z = (v1.z - mean) * rstd * g1.z + b1.z;
    o1.w = (v1.w - mean) * rstd * g1.w + b1.w;
    ((float4*)yp)[t] = o0;
    ((float4*)yp)[t + 256] = o1;
}

extern "C" void kernel_launch(void* const* d_in, const int* in_sizes, int n_in,
                              void* d_out, int out_size, void* d_ws, size_t ws_size,
                              hipStream_t stream) {
    const int* role = (const int*)d_in[0];
    const float* hs = (const float*)d_in[1];
    const float* Wd = (const float*)d_in[2];
    const float* bd = (const float*)d_in[3];
    const float* Wu = (const float*)d_in[4];
    const float* bu = (const float*)d_in[5];
    const float* gamma = (const float*)d_in[6];
    const float* beta = (const float*)d_in[7];
    float* out = (float*)d_out;

    char* ws = (char*)d_ws;
    unsigned short* hs_bf = (unsigned short*)ws;                          // 64 MiB
    unsigned short* wd_t = (unsigned short*)(ws + 67108864);              // 12 MiB  [R][K][H]
    unsigned short* wu_t = (unsigned short*)(ws + 67108864 + 12582912);   // 12 MiB  [R][H][K]
    unsigned short* h_ws = (unsigned short*)(ws + 67108864 + 2 * 12582912); // 32 MiB [BB*S][K]

    cvt_hs<<<4096, 256, 0, stream>>>(hs, hs_bf, (BB * S * H) / 8);
    dim3 tb(32, 8);
    tpose<<<dim3(K / 32, H / 32, R), tb, 0, stream>>>(Wd, wd_t, H, K);
    tpose<<<dim3(H / 32, K / 32, R), tb, 0, stream>>>(Wu, wu_t, K, H);
    gemm_nt<H, 0><<<dim3(K / 128, S / 128, BB), 256, 0, stream>>>(hs_bf, wd_t, role, bd, nullptr, h_ws, K);
    gemm_nt<K, 1><<<dim3(H / 128, S / 128, BB), 256, 0, stream>>>(h_ws, wu_t, role, bu, hs, out, H);
    ln_k<<<BB * S, 256, 0, stream>>>(out, role, gamma, beta);
}

// Round 3
// 302.247 us; speedup vs baseline: 1.0996x; 1.0996x over previous
//
#include <hip/hip_runtime.h>
#include <hip/hip_bf16.h>

#define H 2048
#define K 1024
#define R 3
#define BB 8
#define S 2048

typedef __bf16 bf16x8 __attribute__((ext_vector_type(8)));
typedef float f32x4 __attribute__((ext_vector_type(4)));
typedef unsigned short ushort8 __attribute__((ext_vector_type(8)));

static __device__ __forceinline__ unsigned short f2bf(float f) {
    unsigned int u = __float_as_uint(f);
    u += 0x7FFFu + ((u >> 16) & 1u);   // round-to-nearest-even
    return (unsigned short)(u >> 16);
}

#define GLOAD_LDS16(g, l)                                                      \
    __builtin_amdgcn_global_load_lds(                                          \
        (const __attribute__((address_space(1))) void*)(g),                    \
        (__attribute__((address_space(3))) void*)(l), 16, 0, 0)

// ---------------- convert hidden f32 -> bf16 ----------------
__global__ __launch_bounds__(256) void cvt_hs(const float* __restrict__ in,
                                              unsigned short* __restrict__ out,
                                              int n8) {
    int stride = gridDim.x * blockDim.x;
    for (int i = blockIdx.x * blockDim.x + threadIdx.x; i < n8; i += stride) {
        const float4* p = (const float4*)(in + (size_t)i * 8);
        float4 a = p[0], b = p[1];
        union { unsigned short us[8]; ushort8 v; } o;
        o.us[0] = f2bf(a.x); o.us[1] = f2bf(a.y);
        o.us[2] = f2bf(a.z); o.us[3] = f2bf(a.w);
        o.us[4] = f2bf(b.x); o.us[5] = f2bf(b.y);
        o.us[6] = f2bf(b.z); o.us[7] = f2bf(b.w);
        *(ushort8*)(out + (size_t)i * 8) = o.v;
    }
}

// -------- transpose+convert: in f32 [rows][cols] -> out bf16 [cols][rows] ----
__global__ __launch_bounds__(256) void tpose(const float* __restrict__ in,
                                             unsigned short* __restrict__ out,
                                             int rows, int cols) {
    __shared__ float tile[32][33];
    int rr = blockIdx.z;
    const float* ip = in + (size_t)rr * rows * cols;
    unsigned short* op = out + (size_t)rr * rows * cols;
    int x = blockIdx.x * 32 + threadIdx.x;
    int y0 = blockIdx.y * 32 + threadIdx.y;
#pragma unroll
    for (int j = 0; j < 32; j += 8)
        tile[threadIdx.y + j][threadIdx.x] = ip[(size_t)(y0 + j) * cols + x];
    __syncthreads();
    int ox = blockIdx.y * 32 + threadIdx.x;
    int oy0 = blockIdx.x * 32 + threadIdx.y;
#pragma unroll
    for (int j = 0; j < 32; j += 8)
        op[(size_t)(oy0 + j) * rows + ox] = f2bf(tile[threadIdx.x][threadIdx.y + j]);
}

// ============ pipelined NT GEMM: BM=128, BN=256, BK=64, ring-3 LDS ============
// A: bf16 [BB*S][KC] row-major. Bt: bf16 [R][N][KC] row-major (K-contiguous).
// 512 threads = 8 waves (2 m-waves x 4 n-waves); per-wave 64x64 output.
// LDS ring of 3 slots x (A 16KB + B 32KB) = 144 KiB. Stage tile t+2 during
// tile t; slot (t+2)%3 was last read at tile t-1 (all ds_reads of it complete
// before that iteration's final barrier) -> race-free with counted vmcnt.
// Swizzle (both-sides-or-neither, rule #21): LDS phys col (bits 4-6) holds
// global col phys^((row&7)<<4); read computes the same XOR. The XOR is
// confined to bits 4-6 -> must be applied as XOR on the full (kk,lc) column
// field, NEVER mixed with '+' (round-2 bug: carry from bit 6 into row bits).
// EPI 0: out = bf16 gelu(acc + bias)   EPI 1: out = f32 acc + bias + resid
template <int KC, int EPI>
__global__ __launch_bounds__(512, 2) void gemm_pipe(
    const unsigned short* __restrict__ A, const unsigned short* __restrict__ Bt,
    const int* __restrict__ role, const float* __restrict__ bias,
    const float* __restrict__ resid, void* __restrict__ Out, int N) {
    constexpr int NT = KC / 64;           // K-tiles
    __shared__ char smem[3 * 49152];      // 144 KiB
    const int tid = threadIdx.x;
    const int wid = tid >> 6, lane = tid & 63;
    const int wm = wid >> 2, wn = wid & 3;        // wm 0..1, wn 0..3
    const int lr = lane & 15, lc = lane >> 4;

    // bijective XCD swizzle (gridDim.x % 8 == 0): XCD gets contiguous chunk
    const int nx = N >> 8;                         // N/256 n-tiles
    const int cpx = gridDim.x >> 3;
    const int orig = (blockIdx.x & 7) * cpx + (blockIdx.x >> 3);
    const int tn = orig % nx;
    const int tmz = orig / nx;
    const int tm = tmz & 15;                       // 2048/128 = 16 m-tiles
    const int z = tmz >> 4;
    const int r = role[z];

    const char* Ab = (const char*)(A + ((size_t)z * S + (size_t)tm * 128) * KC);
    const char* Bb = (const char*)(Bt + ((size_t)r * N + (size_t)tn * 256) * KC);

    // staging: one call = 512 thr x 16B = 8KB = 64 rows of 128B
    const int P16 = tid * 16;

#define STAGE_A(slot, kt, c)                                                   \
    do {                                                                       \
        int P_ = (c) * 8192 + P16;                                             \
        int L_ = P_ ^ (((P_ >> 7) & 7) << 4);                                  \
        const char* g_ = Ab + (size_t)(L_ >> 7) * (KC * 2) + (kt) * 128 + (L_ & 127); \
        GLOAD_LDS16(g_, smem + (slot) * 49152 + P_);                           \
    } while (0)
#define STAGE_B(slot, kt, c)                                                   \
    do {                                                                       \
        int P_ = (c) * 8192 + P16;                                             \
        int L_ = P_ ^ (((P_ >> 7) & 7) << 4);                                  \
        const char* g_ = Bb + (size_t)(L_ >> 7) * (KC * 2) + (kt) * 128 + (L_ & 127); \
        GLOAD_LDS16(g_, smem + (slot) * 49152 + 16384 + P_);                   \
    } while (0)

    // prologue: stage tiles 0,1 -> slots 0,1; wait tile-0 loads (12-6=6); join
    STAGE_A(0, 0, 0); STAGE_A(0, 0, 1);
    STAGE_B(0, 0, 0); STAGE_B(0, 0, 1); STAGE_B(0, 0, 2); STAGE_B(0, 0, 3);
    STAGE_A(1, 1, 0); STAGE_A(1, 1, 1);
    STAGE_B(1, 1, 0); STAGE_B(1, 1, 1); STAGE_B(1, 1, 2); STAGE_B(1, 1, 3);
    asm volatile("s_waitcnt vmcnt(6)" ::: "memory");
    __builtin_amdgcn_s_barrier();

    f32x4 acc[4][4] = {};
    const int swz = (lr & 7) << 4;        // row&7 == lr&7 for all our rows

    int slot = 0;
#pragma unroll 1
    for (int t = 0; t < NT; ++t) {
        const char* sa = smem + slot * 49152;
        const char* sb = sa + 16384;
        const int t2 = t + 2;
        int s2 = slot + 2; if (s2 >= 3) s2 -= 3;

        bf16x8 bfr[4][2], afr[2][2];
        // ---- phase 0: read all B frags + A frags i=0,1 ----
#pragma unroll
        for (int j = 0; j < 4; j++)
#pragma unroll
            for (int kk = 0; kk < 2; kk++)
                bfr[j][kk] = *(const bf16x8*)(sb + ((wn * 64 + j * 16 + lr) << 7) +
                                              (((kk << 6) | (lc << 4)) ^ swz));
#pragma unroll
        for (int i = 0; i < 2; i++)
#pragma unroll
            for (int kk = 0; kk < 2; kk++)
                afr[i][kk] = *(const bf16x8*)(sa + ((wm * 64 + i * 16 + lr) << 7) +
                                              (((kk << 6) | (lc << 4)) ^ swz));
        if (t2 < NT) { STAGE_A(s2, t2, 0); STAGE_A(s2, t2, 1); STAGE_B(s2, t2, 0); }
        __builtin_amdgcn_s_barrier();
        asm volatile("s_waitcnt lgkmcnt(0)" ::: "memory");
        __builtin_amdgcn_sched_barrier(0);
        __builtin_amdgcn_s_setprio(1);
#pragma unroll
        for (int kk = 0; kk < 2; kk++)
#pragma unroll
            for (int i = 0; i < 2; i++)
#pragma unroll
                for (int j = 0; j < 4; j++)
                    acc[i][j] = __builtin_amdgcn_mfma_f32_16x16x32_bf16(afr[i][kk], bfr[j][kk], acc[i][j], 0, 0, 0);
        __builtin_amdgcn_s_setprio(0);
        __builtin_amdgcn_s_barrier();

        // ---- phase 1: read A frags i=2,3 ----
#pragma unroll
        for (int i = 0; i < 2; i++)
#pragma unroll
            for (int kk = 0; kk < 2; kk++)
                afr[i][kk] = *(const bf16x8*)(sa + ((wm * 64 + (i + 2) * 16 + lr) << 7) +
                                              (((kk << 6) | (lc << 4)) ^ swz));
        if (t2 < NT) { STAGE_B(s2, t2, 1); STAGE_B(s2, t2, 2); STAGE_B(s2, t2, 3); }
        __builtin_amdgcn_s_barrier();
        asm volatile("s_waitcnt lgkmcnt(0)" ::: "memory");
        __builtin_amdgcn_sched_barrier(0);
        __builtin_amdgcn_s_setprio(1);
#pragma unroll
        for (int kk = 0; kk < 2; kk++)
#pragma unroll
            for (int i = 0; i < 2; i++)
#pragma unroll
                for (int j = 0; j < 4; j++)
                    acc[i + 2][j] = __builtin_amdgcn_mfma_f32_16x16x32_bf16(afr[i][kk], bfr[j][kk], acc[i + 2][j], 0, 0, 0);
        __builtin_amdgcn_s_setprio(0);

        if (t < NT - 1) {
            // need tile t+1 resident for next iter; tile t+2 (6 loads) may fly
            if (t <= NT - 3) asm volatile("s_waitcnt vmcnt(6)" ::: "memory");
            else             asm volatile("s_waitcnt vmcnt(0)" ::: "memory");
            __builtin_amdgcn_s_barrier();
        }
        slot++; if (slot >= 3) slot = 0;
    }
#undef STAGE_A
#undef STAGE_B

    // ---- epilogue ----
    const int base_m = tm * 128 + wm * 64;
    const int base_n = tn * 256 + wn * 64;
    float bn[4];
    const float* bp = bias + (size_t)r * N + base_n;
#pragma unroll
    for (int j = 0; j < 4; j++) bn[j] = bp[j * 16 + lr];

    if (EPI == 0) {
        unsigned short* o = (unsigned short*)Out;
#pragma unroll
        for (int i = 0; i < 4; i++) {
#pragma unroll
            for (int j = 0; j < 4; j++) {
#pragma unroll
                for (int q = 0; q < 4; q++) {
                    size_t grow = (size_t)z * S + base_m + i * 16 + lc * 4 + q;
                    int col = base_n + j * 16 + lr;
                    float x = acc[i][j][q] + bn[j];
                    float g = 0.5f * x * (1.0f + erff(x * 0.70710678118654752f));
                    o[grow * N + col] = f2bf(g);
                }
            }
        }
    } else {
        float* o = (float*)Out;
#pragma unroll
        for (int i = 0; i < 4; i++) {
#pragma unroll
            for (int j = 0; j < 4; j++) {
#pragma unroll
                for (int q = 0; q < 4; q++) {
                    size_t grow = (size_t)z * S + base_m + i * 16 + lc * 4 + q;
                    int col = base_n + j * 16 + lr;
                    float y = acc[i][j][q] + bn[j] + resid[grow * H + col];
                    o[grow * (size_t)N + col] = y;
                }
            }
        }
    }
}

// ---------------- LayerNorm in place on d_out ----------------
__global__ __launch_bounds__(256) void ln_k(float* __restrict__ y,
                                            const int* __restrict__ role,
                                            const float* __restrict__ gamma,
                                            const float* __restrict__ beta) {
    int row = blockIdx.x;
    int z = row / S;
    int r = role[z];
    float* yp = y + (size_t)row * H;
    int t = threadIdx.x;
    float4 v0 = ((const float4*)yp)[t];
    float4 v1 = ((const float4*)yp)[t + 256];
    float s = v0.x + v0.y + v0.z + v0.w + v1.x + v1.y + v1.z + v1.w;
    float ss = v0.x * v0.x + v0.y * v0.y + v0.z * v0.z + v0.w * v0.w +
               v1.x * v1.x + v1.y * v1.y + v1.z * v1.z + v1.w * v1.w;
#pragma unroll
    for (int o = 32; o; o >>= 1) {
        s += __shfl_down(s, o);
        ss += __shfl_down(ss, o);
    }
    __shared__ float ws_s[4], ws_ss[4];
    int wid = t >> 6, lane = t & 63;
    if (lane == 0) { ws_s[wid] = s; ws_ss[wid] = ss; }
    __syncthreads();
    s = ws_s[0] + ws_s[1] + ws_s[2] + ws_s[3];
    ss = ws_ss[0] + ws_ss[1] + ws_ss[2] + ws_ss[3];
    float mean = s * (1.0f / H);
    float var = ss * (1.0f / H) - mean * mean;
    float rstd = rsqrtf(var + 1e-5f);
    const float4* gp = (const float4*)(gamma + (size_t)r * H);
    const float4* bpv = (const float4*)(beta + (size_t)r * H);
    float4 g0 = gp[t], g1 = gp[t + 256];
    float4 b0 = bpv[t], b1 = bpv[t + 256];
    float4 o0, o1;
    o0.x = (v0.x - mean) * rstd * g0.x + b0.x;
    o0.y = (v0.y - mean) * rstd * g0.y + b0.y;
    o0.z = (v0.z - mean) * rstd * g0.z + b0.z;
    o0.w = (v0.w - mean) * rstd * g0.w + b0.w;
    o1.x = (v1.x - mean) * rstd * g1.x + b1.x;
    o1.y = (v1.y - mean) * rstd * g1.y + b1.y;
    o1.z = (v1.z - mean) * rstd * g1.z + b1.z;
    o1.w = (v1.w - mean) * rstd * g1.w + b1.w;
    ((float4*)yp)[t] = o0;
    ((float4*)yp)[t + 256] = o1;
}

extern "C" void kernel_launch(void* const* d_in, const int* in_sizes, int n_in,
                              void* d_out, int out_size, void* d_ws, size_t ws_size,
                              hipStream_t stream) {
    const int* role = (const int*)d_in[0];
    const float* hs = (const float*)d_in[1];
    const float* Wd = (const float*)d_in[2];
    const float* bd = (const float*)d_in[3];
    const float* Wu = (const float*)d_in[4];
    const float* bu = (const float*)d_in[5];
    const float* gamma = (const float*)d_in[6];
    const float* beta = (const float*)d_in[7];
    float* out = (float*)d_out;

    char* ws = (char*)d_ws;
    unsigned short* hs_bf = (unsigned short*)ws;                            // 64 MiB
    unsigned short* wd_t = (unsigned short*)(ws + 67108864);                // 12 MiB [R][K][H]
    unsigned short* wu_t = (unsigned short*)(ws + 67108864 + 12582912);     // 12 MiB [R][H][K]
    unsigned short* h_ws = (unsigned short*)(ws + 67108864 + 2 * 12582912); // 32 MiB [BB*S][K]

    cvt_hs<<<4096, 256, 0, stream>>>(hs, hs_bf, (BB * S * H) / 8);
    dim3 tb(32, 8);
    tpose<<<dim3(K / 32, H / 32, R), tb, 0, stream>>>(Wd, wd_t, H, K);
    tpose<<<dim3(H / 32, K / 32, R), tb, 0, stream>>>(Wu, wu_t, K, H);
    // GEMM1: [16384 x 2048] x [1024 x 2048]^T -> h (bf16, gelu)
    gemm_pipe<H, 0><<<(K / 256) * 16 * BB, 512, 0, stream>>>(hs_bf, wd_t, role, bd, nullptr, h_ws, K);
    // GEMM2: [16384 x 1024] x [2048 x 1024]^T + resid -> out (f32)
    gemm_pipe<K, 1><<<(H / 256) * 16 * BB, 512, 0, stream>>>(h_ws, wu_t, role, bu, hs, out, H);
    ln_k<<<BB * S, 256, 0, stream>>>(out, role, gamma, beta);
}

// Round 4
// 280.028 us; speedup vs baseline: 1.1868x; 1.0793x over previous
//
#include <hip/hip_runtime.h>
#include <hip/hip_bf16.h>

#define H 2048
#define K 1024
#define R 3
#define BB 8
#define S 2048

typedef __bf16 bf16x8 __attribute__((ext_vector_type(8)));
typedef float f32x4 __attribute__((ext_vector_type(4)));
typedef unsigned short ushort8 __attribute__((ext_vector_type(8)));

static __device__ __forceinline__ unsigned short f2bf(float f) {
    unsigned int u = __float_as_uint(f);
    u += 0x7FFFu + ((u >> 16) & 1u);   // round-to-nearest-even
    return (unsigned short)(u >> 16);
}

#define GLOAD_LDS16(g, l)                                                      \
    __builtin_amdgcn_global_load_lds(                                          \
        (const __attribute__((address_space(1))) void*)(g),                    \
        (__attribute__((address_space(3))) void*)(l), 16, 0, 0)

// ---------------- convert hidden f32 -> bf16 ----------------
__global__ __launch_bounds__(256) void cvt_hs(const float* __restrict__ in,
                                              unsigned short* __restrict__ out,
                                              int n8) {
    int stride = gridDim.x * blockDim.x;
    for (int i = blockIdx.x * blockDim.x + threadIdx.x; i < n8; i += stride) {
        const float4* p = (const float4*)(in + (size_t)i * 8);
        float4 a = p[0], b = p[1];
        union { unsigned short us[8]; ushort8 v; } o;
        o.us[0] = f2bf(a.x); o.us[1] = f2bf(a.y);
        o.us[2] = f2bf(a.z); o.us[3] = f2bf(a.w);
        o.us[4] = f2bf(b.x); o.us[5] = f2bf(b.y);
        o.us[6] = f2bf(b.z); o.us[7] = f2bf(b.w);
        *(ushort8*)(out + (size_t)i * 8) = o.v;
    }
}

// -------- transpose+convert: in f32 [rows][cols] -> out bf16 [cols][rows] ----
__global__ __launch_bounds__(256) void tpose(const float* __restrict__ in,
                                             unsigned short* __restrict__ out,
                                             int rows, int cols) {
    __shared__ float tile[32][33];
    int rr = blockIdx.z;
    const float* ip = in + (size_t)rr * rows * cols;
    unsigned short* op = out + (size_t)rr * rows * cols;
    int x = blockIdx.x * 32 + threadIdx.x;
    int y0 = blockIdx.y * 32 + threadIdx.y;
#pragma unroll
    for (int j = 0; j < 32; j += 8)
        tile[threadIdx.y + j][threadIdx.x] = ip[(size_t)(y0 + j) * cols + x];
    __syncthreads();
    int ox = blockIdx.y * 32 + threadIdx.x;
    int oy0 = blockIdx.x * 32 + threadIdx.y;
#pragma unroll
    for (int j = 0; j < 32; j += 8)
        op[(size_t)(oy0 + j) * rows + ox] = f2bf(tile[threadIdx.x][threadIdx.y + j]);
}

// ======== 256x256 8-phase NT GEMM (m201 template port), BK=64, dbuf-2 ========
// A: bf16 [BB*S][KC] row-major. Bt: bf16 [R][N][KC] row-major (K-contiguous).
// 512 thr = 8 waves (2M x 4N); per-wave C = 128x64 (acc[8][4] f32x4).
// LDS 128 KiB: [slot 2][A/B][half 2][128 rows][128 B], XOR-swizzled columns.
// Iter computes K-tiles (t slot0, t+1 slot1) in 8 phases; each phase stages
// one half-tile (2 x global_load_lds). Wave wm reads only A-half wm (phases
// 1-3 / 5-7); wave wn reads only B-half wn>>1 (phases 1-2 / 5-6). Each wave
// drains its own ds_reads (lgkmcnt(0)) before the phase-end barrier, so:
//   slot0-B free after P2, slot0-A after P3, slot1-B after P6, slot1-A after P7
// -> stage plan: P1:(t+1)A0s1  P2:(t+1)A1s1  P3:(t+2)B0s0  P4:(t+2)B1s0
//                P5:(t+2)A0s0  P6:(t+2)A1s0  P7:(t+3)B0s1  P8:(t+3)B1s1
// vmcnt(4) only at P4/P8 (= 2 newest half-tiles may stay in flight).
// EPI 0: out = bf16 gelu(acc+bias)   EPI 1: out = f32 acc+bias+resid
template <int KC, int EPI>
__global__ __launch_bounds__(512, 2) void gemm_8ph(
    const unsigned short* __restrict__ A, const unsigned short* __restrict__ Bt,
    const int* __restrict__ role, const float* __restrict__ bias,
    const float* __restrict__ resid, void* __restrict__ Out, int N) {
    constexpr int NT = KC / 64;
    __shared__ char smem[131072];
    const int tid = threadIdx.x;
    const int wid = tid >> 6, lane = tid & 63;
    const int wm = wid >> 2, wn = wid & 3;
    const int lr = lane & 15, lc = lane >> 4;

    const int nx = N >> 8;
    const int cpx = gridDim.x >> 3;
    const int orig = (blockIdx.x & 7) * cpx + (blockIdx.x >> 3);
    const int tn = orig % nx;
    const int tmz = orig / nx;
    const int tm = tmz & 7;              // S/256 = 8 m-tiles
    const int z = tmz >> 3;
    const int r = role[z];

    const char* Ab = (const char*)(A + ((size_t)z * S + (size_t)tm * 256) * KC);
    const char* Bb = (const char*)(Bt + ((size_t)r * N + (size_t)tn * 256) * KC);

    const int P16 = tid * 16;

#define STAGE_HALF(gbase, ab, half, slot, kt)                                  \
    do {                                                                       \
        _Pragma("unroll") for (int c_ = 0; c_ < 2; c_++) {                     \
            int P_ = c_ * 8192 + P16;                                          \
            int L_ = P_ ^ (((P_ >> 7) & 7) << 4);                              \
            const char* g_ = (gbase) +                                         \
                (size_t)((half) * 128 + (L_ >> 7)) * (KC * 2) +                \
                (size_t)(kt) * 128 + (L_ & 127);                               \
            GLOAD_LDS16(g_, smem + (slot) * 65536 + (ab) * 32768 +             \
                              (half) * 16384 + P_);                            \
        }                                                                      \
    } while (0)

    // prologue: t0 all 4 halves -> slot0; t1 B halves -> slot1
    STAGE_HALF(Ab, 0, 0, 0, 0);
    STAGE_HALF(Ab, 0, 1, 0, 0);
    STAGE_HALF(Bb, 1, 0, 0, 0);
    STAGE_HALF(Bb, 1, 1, 0, 0);
    STAGE_HALF(Bb, 1, 0, 1, 1);
    STAGE_HALF(Bb, 1, 1, 1, 1);
    asm volatile("s_waitcnt vmcnt(4)" ::: "memory");
    __builtin_amdgcn_s_barrier();

    f32x4 acc[8][4] = {};
    const int swz = (lr & 7) << 4;
    const int ck0 = (lc << 4) ^ swz;
    const int ck1 = (0x40 | (lc << 4)) ^ swz;
    const int aBase = wm * 16384 + lr * 128;
    const int bBase = 32768 + (wn >> 1) * 16384 + ((wn & 1) * 64 + lr) * 128;
    const char* sm = smem;

#define LDA4(ibase, pb)                                                        \
    _Pragma("unroll") for (int i_ = 0; i_ < 4; i_++) {                         \
        a[i_][0] = *(const bf16x8*)(sm + (pb) + aBase + ((ibase) + i_) * 2048 + ck0); \
        a[i_][1] = *(const bf16x8*)(sm + (pb) + aBase + ((ibase) + i_) * 2048 + ck1); }
#define LDB2(jbase, pb)                                                        \
    _Pragma("unroll") for (int j_ = 0; j_ < 2; j_++) {                         \
        b[(jbase) + j_][0] = *(const bf16x8*)(sm + (pb) + bBase + ((jbase) + j_) * 2048 + ck0); \
        b[(jbase) + j_][1] = *(const bf16x8*)(sm + (pb) + bBase + ((jbase) + j_) * 2048 + ck1); }
#define MFMA16(IOFF, JOFF)                                                     \
    _Pragma("unroll") for (int kk = 0; kk < 2; kk++)                           \
    _Pragma("unroll") for (int i_ = 0; i_ < 4; i_++)                           \
    _Pragma("unroll") for (int j_ = 0; j_ < 2; j_++)                           \
        acc[(IOFF) + i_][(JOFF) + j_] = __builtin_amdgcn_mfma_f32_16x16x32_bf16( \
            a[i_][kk], b[(JOFF) + j_][kk], acc[(IOFF) + i_][(JOFF) + j_], 0, 0, 0);
#define PH_MID()                                                               \
    __builtin_amdgcn_s_barrier();                                              \
    asm volatile("s_waitcnt lgkmcnt(0)" ::: "memory");                         \
    __builtin_amdgcn_sched_barrier(0);                                         \
    __builtin_amdgcn_s_setprio(1);
#define PH_END()                                                               \
    __builtin_amdgcn_s_setprio(0);                                             \
    __builtin_amdgcn_s_barrier();

#pragma unroll 1
    for (int t = 0; t < NT; t += 2) {
        bf16x8 a[4][2], b[4][2];
        const bool s2ok = (t + 2 < NT), s3ok = (t + 3 < NT);
        // ---- P1: compute (t, i0-3, j0-1) ----
        LDA4(0, 0); LDB2(0, 0);
        STAGE_HALF(Ab, 0, 0, 1, t + 1);
        asm volatile("s_waitcnt lgkmcnt(8)" ::: "memory");
        PH_MID(); MFMA16(0, 0); PH_END();
        // ---- P2: (t, i0-3, j2-3) ----
        LDB2(2, 0);
        STAGE_HALF(Ab, 0, 1, 1, t + 1);
        PH_MID(); MFMA16(0, 2); PH_END();
        // ---- P3: (t, i4-7, j0-1) ----
        LDA4(4, 0);
        if (s2ok) STAGE_HALF(Bb, 1, 0, 0, t + 2);
        PH_MID(); MFMA16(4, 0); PH_END();
        // ---- P4: (t, i4-7, j2-3) + K-tile gate ----
        if (s2ok) STAGE_HALF(Bb, 1, 1, 0, t + 2);
        PH_MID(); MFMA16(4, 2);
        __builtin_amdgcn_s_setprio(0);
        if (s2ok) asm volatile("s_waitcnt vmcnt(4)" ::: "memory");
        else      asm volatile("s_waitcnt vmcnt(0)" ::: "memory");
        __builtin_amdgcn_s_barrier();
        // ---- P5: compute (t+1, i0-3, j0-1) from slot1 ----
        LDA4(0, 65536); LDB2(0, 65536);
        if (s2ok) STAGE_HALF(Ab, 0, 0, 0, t + 2);
        asm volatile("s_waitcnt lgkmcnt(8)" ::: "memory");
        PH_MID(); MFMA16(0, 0); PH_END();
        // ---- P6: (t+1, i0-3, j2-3) ----
        LDB2(2, 65536);
        if (s2ok) STAGE_HALF(Ab, 0, 1, 0, t + 2);
        PH_MID(); MFMA16(0, 2); PH_END();
        // ---- P7: (t+1, i4-7, j0-1) ----
        LDA4(4, 65536);
        if (s3ok) STAGE_HALF(Bb, 1, 0, 1, t + 3);
        PH_MID(); MFMA16(4, 0); PH_END();
        // ---- P8: (t+1, i4-7, j2-3) + K-tile gate ----
        if (s3ok) STAGE_HALF(Bb, 1, 1, 1, t + 3);
        PH_MID(); MFMA16(4, 2);
        __builtin_amdgcn_s_setprio(0);
        if (s2ok) {
            if (s3ok) asm volatile("s_waitcnt vmcnt(4)" ::: "memory");
            else      asm volatile("s_waitcnt vmcnt(0)" ::: "memory");
            __builtin_amdgcn_s_barrier();
        }
    }
#undef STAGE_HALF
#undef LDA4
#undef LDB2
#undef MFMA16
#undef PH_MID
#undef PH_END

    // ---- epilogue ----
    const int base_m = tm * 256 + wm * 128;
    const int base_n = tn * 256 + wn * 64;
    float bn[4];
    const float* bp = bias + (size_t)r * N + base_n;
#pragma unroll
    for (int j = 0; j < 4; j++) bn[j] = bp[j * 16 + lr];

    if (EPI == 0) {
        unsigned short* o = (unsigned short*)Out;
#pragma unroll
        for (int i = 0; i < 8; i++) {
#pragma unroll
            for (int j = 0; j < 4; j++) {
#pragma unroll
                for (int q = 0; q < 4; q++) {
                    size_t grow = (size_t)z * S + base_m + i * 16 + lc * 4 + q;
                    int col = base_n + j * 16 + lr;
                    float x = acc[i][j][q] + bn[j];
                    float g = 0.5f * x * (1.0f + erff(x * 0.70710678118654752f));
                    o[grow * N + col] = f2bf(g);
                }
            }
        }
    } else {
        float* o = (float*)Out;
#pragma unroll
        for (int i = 0; i < 8; i++) {
#pragma unroll
            for (int j = 0; j < 4; j++) {
#pragma unroll
                for (int q = 0; q < 4; q++) {
                    size_t grow = (size_t)z * S + base_m + i * 16 + lc * 4 + q;
                    int col = base_n + j * 16 + lr;
                    float y = acc[i][j][q] + bn[j] + resid[grow * H + col];
                    o[grow * (size_t)N + col] = y;
                }
            }
        }
    }
}

// ---------------- LayerNorm in place on d_out ----------------
__global__ __launch_bounds__(256) void ln_k(float* __restrict__ y,
                                            const int* __restrict__ role,
                                            const float* __restrict__ gamma,
                                            const float* __restrict__ beta) {
    int row = blockIdx.x;
    int z = row / S;
    int r = role[z];
    float* yp = y + (size_t)row * H;
    int t = threadIdx.x;
    float4 v0 = ((const float4*)yp)[t];
    float4 v1 = ((const float4*)yp)[t + 256];
    float s = v0.x + v0.y + v0.z + v0.w + v1.x + v1.y + v1.z + v1.w;
    float ss = v0.x * v0.x + v0.y * v0.y + v0.z * v0.z + v0.w * v0.w +
               v1.x * v1.x + v1.y * v1.y + v1.z * v1.z + v1.w * v1.w;
#pragma unroll
    for (int o = 32; o; o >>= 1) {
        s += __shfl_down(s, o);
        ss += __shfl_down(ss, o);
    }
    __shared__ float ws_s[4], ws_ss[4];
    int wid = t >> 6, lane = t & 63;
    if (lane == 0) { ws_s[wid] = s; ws_ss[wid] = ss; }
    __syncthreads();
    s = ws_s[0] + ws_s[1] + ws_s[2] + ws_s[3];
    ss = ws_ss[0] + ws_ss[1] + ws_ss[2] + ws_ss[3];
    float mean = s * (1.0f / H);
    float var = ss * (1.0f / H) - mean * mean;
    float rstd = rsqrtf(var + 1e-5f);
    const float4* gp = (const float4*)(gamma + (size_t)r * H);
    const float4* bpv = (const float4*)(beta + (size_t)r * H);
    float4 g0 = gp[t], g1 = gp[t + 256];
    float4 b0 = bpv[t], b1 = bpv[t + 256];
    float4 o0, o1;
    o0.x = (v0.x - mean) * rstd * g0.x + b0.x;
    o0.y = (v0.y - mean) * rstd * g0.y + b0.y;
    o0.z = (v0.z - mean) * rstd * g0.z + b0.z;
    o0.w = (v0.w - mean) * rstd * g0.w + b0.w;
    o1.x = (v1.x - mean) * rstd * g1.x + b1.x;
    o1.y = (v1.y - mean) * rstd * g1.y + b1.y;
    o1.z = (v1.z - mean) * rstd * g1.z + b1.z;
    o1.w = (v1.w - mean) * rstd * g1.w + b1.w;
    ((float4*)yp)[t] = o0;
    ((float4*)yp)[t + 256] = o1;
}

extern "C" void kernel_launch(void* const* d_in, const int* in_sizes, int n_in,
                              void* d_out, int out_size, void* d_ws, size_t ws_size,
                              hipStream_t stream) {
    const int* role = (const int*)d_in[0];
    const float* hs = (const float*)d_in[1];
    const float* Wd = (const float*)d_in[2];
    const float* bd = (const float*)d_in[3];
    const float* Wu = (const float*)d_in[4];
    const float* bu = (const float*)d_in[5];
    const float* gamma = (const float*)d_in[6];
    const float* beta = (const float*)d_in[7];
    float* out = (float*)d_out;

    char* ws = (char*)d_ws;
    unsigned short* hs_bf = (unsigned short*)ws;                            // 64 MiB
    unsigned short* wd_t = (unsigned short*)(ws + 67108864);                // 12 MiB [R][K][H]
    unsigned short* wu_t = (unsigned short*)(ws + 67108864 + 12582912);     // 12 MiB [R][H][K]
    unsigned short* h_ws = (unsigned short*)(ws + 67108864 + 2 * 12582912); // 32 MiB [BB*S][K]

    cvt_hs<<<4096, 256, 0, stream>>>(hs, hs_bf, (BB * S * H) / 8);
    dim3 tb(32, 8);
    tpose<<<dim3(K / 32, H / 32, R), tb, 0, stream>>>(Wd, wd_t, H, K);
    tpose<<<dim3(H / 32, K / 32, R), tb, 0, stream>>>(Wu, wu_t, K, H);
    // GEMM1: [16384 x 2048] x [1024 x 2048]^T -> h (bf16, gelu); 256 blocks
    gemm_8ph<H, 0><<<(K / 256) * 8 * BB, 512, 0, stream>>>(hs_bf, wd_t, role, bd, nullptr, h_ws, K);
    // GEMM2: [16384 x 1024] x [2048 x 1024]^T + resid -> out (f32); 512 blocks
    gemm_8ph<K, 1><<<(H / 256) * 8 * BB, 512, 0, stream>>>(h_ws, wu_t, role, bu, hs, out, H);
    ln_k<<<BB * S, 256, 0, stream>>>(out, role, gamma, beta);
}

// Round 5
// 276.023 us; speedup vs baseline: 1.2040x; 1.0145x over previous
//
#include <hip/hip_runtime.h>
#include <hip/hip_bf16.h>

#define H 2048
#define K 1024
#define R 3
#define BB 8
#define S 2048

typedef __bf16 bf16x8 __attribute__((ext_vector_type(8)));
typedef float f32x4 __attribute__((ext_vector_type(4)));
typedef unsigned short ushort8 __attribute__((ext_vector_type(8)));

static __device__ __forceinline__ unsigned short f2bf(float f) {
    unsigned int u = __float_as_uint(f);
    u += 0x7FFFu + ((u >> 16) & 1u);   // round-to-nearest-even
    return (unsigned short)(u >> 16);
}

#define GLOAD_LDS16(g, l)                                                      \
    __builtin_amdgcn_global_load_lds(                                          \
        (const __attribute__((address_space(1))) void*)(g),                    \
        (__attribute__((address_space(3))) void*)(l), 16, 0, 0)

// ---------------- convert hidden f32 -> bf16 ----------------
__global__ __launch_bounds__(256) void cvt_hs(const float* __restrict__ in,
                                              unsigned short* __restrict__ out,
                                              int n8) {
    int stride = gridDim.x * blockDim.x;
    for (int i = blockIdx.x * blockDim.x + threadIdx.x; i < n8; i += stride) {
        const float4* p = (const float4*)(in + (size_t)i * 8);
        float4 a = p[0], b = p[1];
        union { unsigned short us[8]; ushort8 v; } o;
        o.us[0] = f2bf(a.x); o.us[1] = f2bf(a.y);
        o.us[2] = f2bf(a.z); o.us[3] = f2bf(a.w);
        o.us[4] = f2bf(b.x); o.us[5] = f2bf(b.y);
        o.us[6] = f2bf(b.z); o.us[7] = f2bf(b.w);
        *(ushort8*)(out + (size_t)i * 8) = o.v;
    }
}

// -------- transpose+convert: in f32 [rows][cols] -> out bf16 [cols][rows] ----
__global__ __launch_bounds__(256) void tpose(const float* __restrict__ in,
                                             unsigned short* __restrict__ out,
                                             int rows, int cols) {
    __shared__ float tile[32][33];
    int rr = blockIdx.z;
    const float* ip = in + (size_t)rr * rows * cols;
    unsigned short* op = out + (size_t)rr * rows * cols;
    int x = blockIdx.x * 32 + threadIdx.x;
    int y0 = blockIdx.y * 32 + threadIdx.y;
#pragma unroll
    for (int j = 0; j < 32; j += 8)
        tile[threadIdx.y + j][threadIdx.x] = ip[(size_t)(y0 + j) * cols + x];
    __syncthreads();
    int ox = blockIdx.y * 32 + threadIdx.x;
    int oy0 = blockIdx.x * 32 + threadIdx.y;
#pragma unroll
    for (int j = 0; j < 32; j += 8)
        op[(size_t)(oy0 + j) * rows + ox] = f2bf(tile[threadIdx.x][threadIdx.y + j]);
}

// ==== 256x256 8-phase NT GEMM, BK=64, A-ring-3 + B-dbuf-2, deep vmcnt(8) ====
// LDS 160 KiB: A: 3 slots x [256 rows][128B] (96 KB, slot = tile%3);
//              B: 2 slots x [256 rows][128B] (64 KB, slot = tile&1), at 98304.
// Iter t (even; computes tiles t,t+1), stages per phase (each = 1 half-tile
// = 2 x global_load_lds): P1/P2: A(t+2)->slot(t+2)%3; P3/P4: B(t+2)->bslot0;
// P5/P6: A(t+3)->slot t%3; P7/P8: B(t+3)->bslot1.
// Gates vmcnt(8) at P4 and P8: at P4, outstanding = prev P5-P8 (8) + this
// P1-P4 (8); forces prev iter's A(t+1)/B(t+1) -- issued 7-8 phases earlier
// (>= HBM miss latency), needed at P5. At P8 forces this iter's t+2 stages
// (4-7 phases old), needed next P1. Slot WAR safety: every overwritten slot's
// last ds_read drained >=1 phase-barrier earlier (per-phase lgkmcnt(0)).
// EPI 0: out = bf16 gelu(acc+bias) -> h
// EPI 1: out = bf16 (acc+bias+resid_f32); per-block row sum/sumsq -> Part
template <int KC, int EPI>
__global__ __launch_bounds__(512, 2) void gemm_8ph(
    const unsigned short* __restrict__ A, const unsigned short* __restrict__ Bt,
    const int* __restrict__ role, const float* __restrict__ bias,
    const float* __restrict__ resid, void* __restrict__ Out,
    float2* __restrict__ Part, int N) {
    constexpr int NT = KC / 64;
    __shared__ char smem[163840];
    const int tid = threadIdx.x;
    const int wid = tid >> 6, lane = tid & 63;
    const int wm = wid >> 2, wn = wid & 3;
    const int lr = lane & 15, lc = lane >> 4;

    const int nx = N >> 8;
    const int cpx = gridDim.x >> 3;
    const int orig = (blockIdx.x & 7) * cpx + (blockIdx.x >> 3);
    const int tn = orig % nx;
    const int tmz = orig / nx;
    const int tm = tmz & 7;              // S/256 = 8 m-tiles
    const int z = tmz >> 3;
    const int r = role[z];

    const char* Ab = (const char*)(A + ((size_t)z * S + (size_t)tm * 256) * KC);
    const char* Bb = (const char*)(Bt + ((size_t)r * N + (size_t)tn * 256) * KC);

    const int P16 = tid * 16;

    // stage ONE half-tile (128 rows x 128B) = 2 x global_load_lds(16B)
#define STAGE16(gbase, ldsbase, kt, half)                                      \
    do {                                                                       \
        _Pragma("unroll") for (int c_ = 0; c_ < 2; c_++) {                     \
            int P_ = c_ * 8192 + P16;                                          \
            int L_ = P_ ^ (((P_ >> 7) & 7) << 4);                              \
            const char* g_ = (gbase) +                                         \
                (size_t)((half) * 128 + (L_ >> 7)) * (KC * 2) +                \
                (size_t)(kt) * 128 + (L_ & 127);                               \
            GLOAD_LDS16(g_, (ldsbase) + (half) * 16384 + P_);                  \
        }                                                                      \
    } while (0)

    // prologue: A(0)->slot0, B(0)->bslot0, A(1)->slot1, B(1)->bslot1
    STAGE16(Ab, smem, 0, 0);            STAGE16(Ab, smem, 0, 1);
    STAGE16(Bb, smem + 98304, 0, 0);    STAGE16(Bb, smem + 98304, 0, 1);
    STAGE16(Ab, smem + 32768, 1, 0);    STAGE16(Ab, smem + 32768, 1, 1);
    STAGE16(Bb, smem + 131072, 1, 0);   STAGE16(Bb, smem + 131072, 1, 1);
    asm volatile("s_waitcnt vmcnt(8)" ::: "memory");   // force A(0),B(0)
    __builtin_amdgcn_s_barrier();

    f32x4 acc[8][4] = {};
    const int swz = (lr & 7) << 4;
    const int ck0 = (lc << 4) ^ swz;
    const int ck1 = ck0 ^ 0x40;
    const char* sm = smem;

#define LDA4(ibase, base_)                                                     \
    _Pragma("unroll") for (int i_ = 0; i_ < 4; i_++) {                         \
        int rb_ = (wm * 128 + ((ibase) + i_) * 16 + lr) << 7;                  \
        a[i_][0] = *(const bf16x8*)(sm + (base_) + rb_ + ck0);                 \
        a[i_][1] = *(const bf16x8*)(sm + (base_) + rb_ + ck1); }
#define LDB2(jbase, base_)                                                     \
    _Pragma("unroll") for (int j_ = 0; j_ < 2; j_++) {                         \
        int rb_ = (wn * 64 + ((jbase) + j_) * 16 + lr) << 7;                   \
        b[(jbase) + j_][0] = *(const bf16x8*)(sm + 98304 + (base_) + rb_ + ck0); \
        b[(jbase) + j_][1] = *(const bf16x8*)(sm + 98304 + (base_) + rb_ + ck1); }
#define MFMA16(IOFF, JOFF)                                                     \
    _Pragma("unroll") for (int kk = 0; kk < 2; kk++)                           \
    _Pragma("unroll") for (int i_ = 0; i_ < 4; i_++)                           \
    _Pragma("unroll") for (int j_ = 0; j_ < 2; j_++)                           \
        acc[(IOFF) + i_][(JOFF) + j_] = __builtin_amdgcn_mfma_f32_16x16x32_bf16( \
            a[i_][kk], b[(JOFF) + j_][kk], acc[(IOFF) + i_][(JOFF) + j_], 0, 0, 0);
#define PH_MID()                                                               \
    __builtin_amdgcn_s_barrier();                                              \
    asm volatile("s_waitcnt lgkmcnt(0)" ::: "memory");                         \
    __builtin_amdgcn_sched_barrier(0);                                         \
    __builtin_amdgcn_s_setprio(1);
#define PH_END()                                                               \
    __builtin_amdgcn_s_setprio(0);                                             \
    __builtin_amdgcn_s_barrier();

    int as0 = 0, as1 = 1, as2 = 2;       // (t)%3, (t+1)%3, (t+2)%3
#pragma unroll 1
    for (int t = 0; t < NT; t += 2) {
        bf16x8 a[4][2], b[4][2];
        const bool pf = (t + 2) < NT;
        const int saT = as0 * 32768, saT1 = as1 * 32768;
        char* stA2 = smem + as2 * 32768;
        char* stA3 = smem + as0 * 32768;
        // ---- P1: compute (t, i0-3, j0-1) ----
        LDA4(0, saT); LDB2(0, 0);
        if (pf) STAGE16(Ab, stA2, t + 2, 0);
        asm volatile("s_waitcnt lgkmcnt(8)" ::: "memory");
        PH_MID(); MFMA16(0, 0); PH_END();
        // ---- P2: (t, i0-3, j2-3) ----
        LDB2(2, 0);
        if (pf) STAGE16(Ab, stA2, t + 2, 1);
        PH_MID(); MFMA16(0, 2); PH_END();
        // ---- P3: (t, i4-7, j0-1) ----
        LDA4(4, saT);
        if (pf) STAGE16(Bb, smem + 98304, t + 2, 0);
        PH_MID(); MFMA16(4, 0); PH_END();
        // ---- P4: (t, i4-7, j2-3) + gate ----
        if (pf) STAGE16(Bb, smem + 98304, t + 2, 1);
        PH_MID(); MFMA16(4, 2);
        __builtin_amdgcn_s_setprio(0);
        if (pf) asm volatile("s_waitcnt vmcnt(8)" ::: "memory");
        else    asm volatile("s_waitcnt vmcnt(0)" ::: "memory");
        __builtin_amdgcn_s_barrier();
        // ---- P5: compute (t+1, i0-3, j0-1) ----
        LDA4(0, saT1); LDB2(0, 32768);
        if (pf) STAGE16(Ab, stA3, t + 3, 0);
        asm volatile("s_waitcnt lgkmcnt(8)" ::: "memory");
        PH_MID(); MFMA16(0, 0); PH_END();
        // ---- P6: (t+1, i0-3, j2-3) ----
        LDB2(2, 32768);
        if (pf) STAGE16(Ab, stA3, t + 3, 1);
        PH_MID(); MFMA16(0, 2); PH_END();
        // ---- P7: (t+1, i4-7, j0-1) ----
        LDA4(4, saT1);
        if (pf) STAGE16(Bb, smem + 131072, t + 3, 0);
        PH_MID(); MFMA16(4, 0); PH_END();
        // ---- P8: (t+1, i4-7, j2-3) + gate ----
        if (pf) STAGE16(Bb, smem + 131072, t + 3, 1);
        PH_MID(); MFMA16(4, 2);
        __builtin_amdgcn_s_setprio(0);
        if (pf) {
            asm volatile("s_waitcnt vmcnt(8)" ::: "memory");
            __builtin_amdgcn_s_barrier();
        }
        int t0 = as0; as0 = as2; as2 = as1; as1 = t0;   // rotate %3 slots
    }
#undef STAGE16
#undef LDA4
#undef LDB2
#undef MFMA16
#undef PH_MID
#undef PH_END

    // ---- epilogue ----
    const int base_m = tm * 256 + wm * 128;
    const int base_n = tn * 256 + wn * 64;
    float bn[4];
    const float* bp = bias + (size_t)r * N + base_n;
#pragma unroll
    for (int j = 0; j < 4; j++) bn[j] = bp[j * 16 + lr];

    if (EPI == 0) {
        unsigned short* o = (unsigned short*)Out;
#pragma unroll
        for (int i = 0; i < 8; i++) {
#pragma unroll
            for (int j = 0; j < 4; j++) {
#pragma unroll
                for (int q = 0; q < 4; q++) {
                    size_t grow = (size_t)z * S + base_m + i * 16 + lc * 4 + q;
                    int col = base_n + j * 16 + lr;
                    float x = acc[i][j][q] + bn[j];
                    float g = 0.5f * x * (1.0f + erff(x * 0.70710678118654752f));
                    o[grow * N + col] = f2bf(g);
                }
            }
        }
    } else {
        unsigned short* o = (unsigned short*)Out;     // y bf16 [BB*S][N]
        float* pl = (float*)smem;                     // [8][256] partials
        __syncthreads();
#pragma unroll
        for (int i = 0; i < 8; i++) {
#pragma unroll
            for (int q = 0; q < 4; q++) {
                size_t grow = (size_t)z * S + base_m + i * 16 + lc * 4 + q;
                float s = 0.f, sq = 0.f;
#pragma unroll
                for (int j = 0; j < 4; j++) {
                    int col = base_n + j * 16 + lr;
                    float y = acc[i][j][q] + bn[j] + resid[grow * H + col];
                    o[grow * (size_t)N + col] = f2bf(y);
                    s += y; sq += y * y;
                }
#pragma unroll
                for (int off = 1; off < 16; off <<= 1) {
                    s  += __shfl_xor(s, off);
                    sq += __shfl_xor(sq, off);
                }
                if (lr == 0) {
                    int rloc = wm * 128 + i * 16 + lc * 4 + q;
                    pl[wn * 256 + rloc] = s;
                    pl[(4 + wn) * 256 + rloc] = sq;
                }
            }
        }
        __syncthreads();
        if (tid < 256) {
            float s  = pl[tid] + pl[256 + tid] + pl[512 + tid] + pl[768 + tid];
            float sq = pl[1024 + tid] + pl[1280 + tid] + pl[1536 + tid] + pl[1792 + tid];
            size_t grow = (size_t)z * S + tm * 256 + tid;
            Part[(size_t)tn * (BB * S) + grow] = make_float2(s, sq);
        }
    }
}

// ------- LayerNorm: partials + y(bf16) -> out(f32), one block per row -------
__global__ __launch_bounds__(256) void ln2(const unsigned short* __restrict__ ybf,
                                           const float2* __restrict__ part,
                                           const int* __restrict__ role,
                                           const float* __restrict__ gamma,
                                           const float* __restrict__ beta,
                                           float* __restrict__ out) {
    int row = blockIdx.x;
    int z = row >> 11;                 // row / S
    int r = role[z];
    float s = 0.f, ss = 0.f;
#pragma unroll
    for (int nb = 0; nb < 8; nb++) {
        float2 p = part[(size_t)nb * (BB * S) + row];
        s += p.x; ss += p.y;
    }
    float mean = s * (1.0f / H);
    float var = ss * (1.0f / H) - mean * mean;
    float rstd = rsqrtf(var + 1e-5f);
    int t = threadIdx.x;
    ushort8 yv = ((const ushort8*)(ybf + (size_t)row * H))[t];
    const float4* gp = (const float4*)(gamma + (size_t)r * H);
    const float4* bp = (const float4*)(beta + (size_t)r * H);
    float4 g0 = gp[2 * t], g1 = gp[2 * t + 1];
    float4 b0 = bp[2 * t], b1 = bp[2 * t + 1];
    float yo[8];
#pragma unroll
    for (int e = 0; e < 8; e++)
        yo[e] = (__uint_as_float(((unsigned)yv[e]) << 16) - mean) * rstd;
    float4 r0, r1;
    r0.x = yo[0] * g0.x + b0.x; r0.y = yo[1] * g0.y + b0.y;
    r0.z = yo[2] * g0.z + b0.z; r0.w = yo[3] * g0.w + b0.w;
    r1.x = yo[4] * g1.x + b1.x; r1.y = yo[5] * g1.y + b1.y;
    r1.z = yo[6] * g1.z + b1.z; r1.w = yo[7] * g1.w + b1.w;
    float4* op = (float4*)(out + (size_t)row * H);
    op[2 * t] = r0;
    op[2 * t + 1] = r1;
}

extern "C" void kernel_launch(void* const* d_in, const int* in_sizes, int n_in,
                              void* d_out, int out_size, void* d_ws, size_t ws_size,
                              hipStream_t stream) {
    const int* role = (const int*)d_in[0];
    const float* hs = (const float*)d_in[1];
    const float* Wd = (const float*)d_in[2];
    const float* bd = (const float*)d_in[3];
    const float* Wu = (const float*)d_in[4];
    const float* bu = (const float*)d_in[5];
    const float* gamma = (const float*)d_in[6];
    const float* beta = (const float*)d_in[7];
    float* out = (float*)d_out;

    char* ws = (char*)d_ws;
    // region A (64 MiB @0): hs_bf (cvt -> G1), then y_bf (G2 -> LN)
    unsigned short* hs_bf = (unsigned short*)ws;
    unsigned short* y_bf = (unsigned short*)ws;
    // region B (12 MiB @64Mi): wd_t (tpose -> G1), then partials (G2 -> LN)
    unsigned short* wd_t = (unsigned short*)(ws + 67108864);
    float2* part = (float2*)(ws + 67108864);
    // region C (12 MiB @76Mi): wu_t
    unsigned short* wu_t = (unsigned short*)(ws + 67108864 + 12582912);
    // region D (32 MiB @88Mi): h
    unsigned short* h_ws = (unsigned short*)(ws + 67108864 + 2 * 12582912);

    cvt_hs<<<4096, 256, 0, stream>>>(hs, hs_bf, (BB * S * H) / 8);
    dim3 tb(32, 8);
    tpose<<<dim3(K / 32, H / 32, R), tb, 0, stream>>>(Wd, wd_t, H, K);
    tpose<<<dim3(H / 32, K / 32, R), tb, 0, stream>>>(Wu, wu_t, K, H);
    // GEMM1: h = gelu(hs_bf x Wd^T + bd), bf16; 256 blocks
    gemm_8ph<H, 0><<<(K / 256) * 8 * BB, 512, 0, stream>>>(hs_bf, wd_t, role, bd,
                                                           nullptr, h_ws, nullptr, K);
    // GEMM2: y = h x Wu^T + bu + hs(f32), bf16 + partial stats; 512 blocks
    gemm_8ph<K, 1><<<(H / 256) * 8 * BB, 512, 0, stream>>>(h_ws, wu_t, role, bu,
                                                           hs, y_bf, part, H);
    ln2<<<BB * S, 256, 0, stream>>>(y_bf, part, role, gamma, beta, out);
}

// Round 6
// 256.566 us; speedup vs baseline: 1.2954x; 1.0758x over previous
//
#include <hip/hip_runtime.h>
#include <hip/hip_bf16.h>

#define H 2048
#define K 1024
#define R 3
#define BB 8
#define S 2048

typedef __bf16 bf16x8 __attribute__((ext_vector_type(8)));
typedef float f32x4 __attribute__((ext_vector_type(4)));
typedef unsigned short ushort8 __attribute__((ext_vector_type(8)));

static __device__ __forceinline__ unsigned short f2bf(float f) {
    unsigned int u = __float_as_uint(f);
    u += 0x7FFFu + ((u >> 16) & 1u);   // round-to-nearest-even
    return (unsigned short)(u >> 16);
}

#define GLOAD_LDS16(g, l)                                                      \
    __builtin_amdgcn_global_load_lds(                                          \
        (const __attribute__((address_space(1))) void*)(g),                    \
        (__attribute__((address_space(3))) void*)(l), 16, 0, 0)

// ---------------- convert hidden f32 -> bf16 ----------------
__global__ __launch_bounds__(256) void cvt_hs(const float* __restrict__ in,
                                              unsigned short* __restrict__ out,
                                              int n8) {
    int stride = gridDim.x * blockDim.x;
    for (int i = blockIdx.x * blockDim.x + threadIdx.x; i < n8; i += stride) {
        const float4* p = (const float4*)(in + (size_t)i * 8);
        float4 a = p[0], b = p[1];
        union { unsigned short us[8]; ushort8 v; } o;
        o.us[0] = f2bf(a.x); o.us[1] = f2bf(a.y);
        o.us[2] = f2bf(a.z); o.us[3] = f2bf(a.w);
        o.us[4] = f2bf(b.x); o.us[5] = f2bf(b.y);
        o.us[6] = f2bf(b.z); o.us[7] = f2bf(b.w);
        *(ushort8*)(out + (size_t)i * 8) = o.v;
    }
}

// -------- transpose+convert: in f32 [rows][cols] -> out bf16 [cols][rows] ----
__global__ __launch_bounds__(256) void tpose(const float* __restrict__ in,
                                             unsigned short* __restrict__ out,
                                             int rows, int cols) {
    __shared__ float tile[32][33];
    int rr = blockIdx.z;
    const float* ip = in + (size_t)rr * rows * cols;
    unsigned short* op = out + (size_t)rr * rows * cols;
    int x = blockIdx.x * 32 + threadIdx.x;
    int y0 = blockIdx.y * 32 + threadIdx.y;
#pragma unroll
    for (int j = 0; j < 32; j += 8)
        tile[threadIdx.y + j][threadIdx.x] = ip[(size_t)(y0 + j) * cols + x];
    __syncthreads();
    int ox = blockIdx.y * 32 + threadIdx.x;
    int oy0 = blockIdx.x * 32 + threadIdx.y;
#pragma unroll
    for (int j = 0; j < 32; j += 8)
        op[(size_t)(oy0 + j) * rows + ox] = f2bf(tile[threadIdx.x][threadIdx.y + j]);
}

// ==== 256x256 8-phase NT GEMM, BK=64, A-ring-3 + B-dbuf-2, deep vmcnt(8) ====
// Phase = {ds_reads; stage; barrier; lgkmcnt(0); setprio(1); 16 MFMA;
// setprio(0); barrier}. NO sched_barrier(0): ds_reads are compiler-visible
// loads, so the compiler emits derived fine-grained lgkmcnt per MFMA group
// and may interleave address VALU into the MFMA burst (m141: sched_barrier
// pinning costs 1.7x on this class). Counted vmcnt(8) gates only at P4/P8.
// EPI 0: out = bf16 gelu(acc+bias) -> h
// EPI 1: out = bf16 (acc+bias+resid_bf16) IN PLACE over resid; row stats->Part
template <int KC, int EPI>
__global__ __launch_bounds__(512, 2) void gemm_8ph(
    const unsigned short* __restrict__ A, const unsigned short* __restrict__ Bt,
    const int* __restrict__ role, const float* __restrict__ bias,
    const unsigned short* __restrict__ resid, void* __restrict__ Out,
    float2* __restrict__ Part, int N) {
    constexpr int NT = KC / 64;
    __shared__ char smem[163840];
    const int tid = threadIdx.x;
    const int wid = tid >> 6, lane = tid & 63;
    const int wm = wid >> 2, wn = wid & 3;
    const int lr = lane & 15, lc = lane >> 4;

    const int nx = N >> 8;
    const int cpx = gridDim.x >> 3;
    const int orig = (blockIdx.x & 7) * cpx + (blockIdx.x >> 3);
    const int tn = orig % nx;
    const int tmz = orig / nx;
    const int tm = tmz & 7;              // S/256 = 8 m-tiles
    const int z = tmz >> 3;
    const int r = role[z];

    const char* Ab = (const char*)(A + ((size_t)z * S + (size_t)tm * 256) * KC);
    const char* Bb = (const char*)(Bt + ((size_t)r * N + (size_t)tn * 256) * KC);

    const int P16 = tid * 16;

    // stage ONE half-tile (128 rows x 128B) = 2 x global_load_lds(16B)
#define STAGE16(gbase, ldsbase, kt, half)                                      \
    do {                                                                       \
        _Pragma("unroll") for (int c_ = 0; c_ < 2; c_++) {                     \
            int P_ = c_ * 8192 + P16;                                          \
            int L_ = P_ ^ (((P_ >> 7) & 7) << 4);                              \
            const char* g_ = (gbase) +                                         \
                (size_t)((half) * 128 + (L_ >> 7)) * (KC * 2) +                \
                (size_t)(kt) * 128 + (L_ & 127);                               \
            GLOAD_LDS16(g_, (ldsbase) + (half) * 16384 + P_);                  \
        }                                                                      \
    } while (0)

    // prologue: A(0)->slot0, B(0)->bslot0, A(1)->slot1, B(1)->bslot1
    STAGE16(Ab, smem, 0, 0);            STAGE16(Ab, smem, 0, 1);
    STAGE16(Bb, smem + 98304, 0, 0);    STAGE16(Bb, smem + 98304, 0, 1);
    STAGE16(Ab, smem + 32768, 1, 0);    STAGE16(Ab, smem + 32768, 1, 1);
    STAGE16(Bb, smem + 131072, 1, 0);   STAGE16(Bb, smem + 131072, 1, 1);
    asm volatile("s_waitcnt vmcnt(8)" ::: "memory");   // force A(0),B(0)
    __builtin_amdgcn_s_barrier();

    f32x4 acc[8][4] = {};
    const int swz = (lr & 7) << 4;
    const int ck0 = (lc << 4) ^ swz;
    const int ck1 = ck0 ^ 0x40;
    const char* sm = smem;

#define LDA4(ibase, base_)                                                     \
    _Pragma("unroll") for (int i_ = 0; i_ < 4; i_++) {                         \
        int rb_ = (wm * 128 + ((ibase) + i_) * 16 + lr) << 7;                  \
        a[i_][0] = *(const bf16x8*)(sm + (base_) + rb_ + ck0);                 \
        a[i_][1] = *(const bf16x8*)(sm + (base_) + rb_ + ck1); }
#define LDB2(jbase, base_)                                                     \
    _Pragma("unroll") for (int j_ = 0; j_ < 2; j_++) {                         \
        int rb_ = (wn * 64 + ((jbase) + j_) * 16 + lr) << 7;                   \
        b[(jbase) + j_][0] = *(const bf16x8*)(sm + 98304 + (base_) + rb_ + ck0); \
        b[(jbase) + j_][1] = *(const bf16x8*)(sm + 98304 + (base_) + rb_ + ck1); }
#define MFMA16(IOFF, JOFF)                                                     \
    _Pragma("unroll") for (int kk = 0; kk < 2; kk++)                           \
    _Pragma("unroll") for (int i_ = 0; i_ < 4; i_++)                           \
    _Pragma("unroll") for (int j_ = 0; j_ < 2; j_++)                           \
        acc[(IOFF) + i_][(JOFF) + j_] = __builtin_amdgcn_mfma_f32_16x16x32_bf16( \
            a[i_][kk], b[(JOFF) + j_][kk], acc[(IOFF) + i_][(JOFF) + j_], 0, 0, 0);
#define PH_MID()                                                               \
    __builtin_amdgcn_s_barrier();                                              \
    asm volatile("s_waitcnt lgkmcnt(0)" ::: "memory");                         \
    __builtin_amdgcn_s_setprio(1);
#define PH_END()                                                               \
    __builtin_amdgcn_s_setprio(0);                                             \
    __builtin_amdgcn_s_barrier();

    int as0 = 0, as1 = 1, as2 = 2;       // (t)%3, (t+1)%3, (t+2)%3
#pragma unroll 1
    for (int t = 0; t < NT; t += 2) {
        bf16x8 a[4][2], b[4][2];
        const bool pf = (t + 2) < NT;
        const int saT = as0 * 32768, saT1 = as1 * 32768;
        char* stA2 = smem + as2 * 32768;
        char* stA3 = smem + as0 * 32768;
        // ---- P1: compute (t, i0-3, j0-1) ----
        LDA4(0, saT); LDB2(0, 0);
        if (pf) STAGE16(Ab, stA2, t + 2, 0);
        asm volatile("s_waitcnt lgkmcnt(8)" ::: "memory");
        PH_MID(); MFMA16(0, 0); PH_END();
        // ---- P2: (t, i0-3, j2-3) ----
        LDB2(2, 0);
        if (pf) STAGE16(Ab, stA2, t + 2, 1);
        PH_MID(); MFMA16(0, 2); PH_END();
        // ---- P3: (t, i4-7, j0-1) ----
        LDA4(4, saT);
        if (pf) STAGE16(Bb, smem + 98304, t + 2, 0);
        PH_MID(); MFMA16(4, 0); PH_END();
        // ---- P4: (t, i4-7, j2-3) + gate ----
        if (pf) STAGE16(Bb, smem + 98304, t + 2, 1);
        PH_MID(); MFMA16(4, 2);
        __builtin_amdgcn_s_setprio(0);
        if (pf) asm volatile("s_waitcnt vmcnt(8)" ::: "memory");
        else    asm volatile("s_waitcnt vmcnt(0)" ::: "memory");
        __builtin_amdgcn_s_barrier();
        // ---- P5: compute (t+1, i0-3, j0-1) ----
        LDA4(0, saT1); LDB2(0, 32768);
        if (pf) STAGE16(Ab, stA3, t + 3, 0);
        asm volatile("s_waitcnt lgkmcnt(8)" ::: "memory");
        PH_MID(); MFMA16(0, 0); PH_END();
        // ---- P6: (t+1, i0-3, j2-3) ----
        LDB2(2, 32768);
        if (pf) STAGE16(Ab, stA3, t + 3, 1);
        PH_MID(); MFMA16(0, 2); PH_END();
        // ---- P7: (t+1, i4-7, j0-1) ----
        LDA4(4, saT1);
        if (pf) STAGE16(Bb, smem + 131072, t + 3, 0);
        PH_MID(); MFMA16(4, 0); PH_END();
        // ---- P8: (t+1, i4-7, j2-3) + gate ----
        if (pf) STAGE16(Bb, smem + 131072, t + 3, 1);
        PH_MID(); MFMA16(4, 2);
        __builtin_amdgcn_s_setprio(0);
        if (pf) {
            asm volatile("s_waitcnt vmcnt(8)" ::: "memory");
            __builtin_amdgcn_s_barrier();
        }
        int t0 = as0; as0 = as2; as2 = as1; as1 = t0;   // rotate %3 slots
    }
#undef STAGE16
#undef LDA4
#undef LDB2
#undef MFMA16
#undef PH_MID
#undef PH_END

    // ---- epilogue ----
    const int base_m = tm * 256 + wm * 128;
    const int base_n = tn * 256 + wn * 64;
    float bn[4];
    const float* bp = bias + (size_t)r * N + base_n;
#pragma unroll
    for (int j = 0; j < 4; j++) bn[j] = bp[j * 16 + lr];

    if (EPI == 0) {
        unsigned short* o = (unsigned short*)Out;
#pragma unroll
        for (int i = 0; i < 8; i++) {
#pragma unroll
            for (int j = 0; j < 4; j++) {
#pragma unroll
                for (int q = 0; q < 4; q++) {
                    size_t grow = (size_t)z * S + base_m + i * 16 + lc * 4 + q;
                    int col = base_n + j * 16 + lr;
                    float x = acc[i][j][q] + bn[j];
                    float g = 0.5f * x * (1.0f + erff(x * 0.70710678118654752f));
                    o[grow * N + col] = f2bf(g);
                }
            }
        }
    } else {
        unsigned short* o = (unsigned short*)Out;     // y bf16 (in place on resid)
        float* pl = (float*)smem;                     // [8][256] partials
        __syncthreads();
#pragma unroll
        for (int i = 0; i < 8; i++) {
#pragma unroll
            for (int q = 0; q < 4; q++) {
                size_t grow = (size_t)z * S + base_m + i * 16 + lc * 4 + q;
                float s = 0.f, sq = 0.f;
#pragma unroll
                for (int j = 0; j < 4; j++) {
                    int col = base_n + j * 16 + lr;
                    float rv = __uint_as_float(((unsigned)resid[grow * (size_t)N + col]) << 16);
                    float y = acc[i][j][q] + bn[j] + rv;
                    o[grow * (size_t)N + col] = f2bf(y);
                    s += y; sq += y * y;
                }
#pragma unroll
                for (int off = 1; off < 16; off <<= 1) {
                    s  += __shfl_xor(s, off);
                    sq += __shfl_xor(sq, off);
                }
                if (lr == 0) {
                    int rloc = wm * 128 + i * 16 + lc * 4 + q;
                    pl[wn * 256 + rloc] = s;
                    pl[(4 + wn) * 256 + rloc] = sq;
                }
            }
        }
        __syncthreads();
        if (tid < 256) {
            float s  = pl[tid] + pl[256 + tid] + pl[512 + tid] + pl[768 + tid];
            float sq = pl[1024 + tid] + pl[1280 + tid] + pl[1536 + tid] + pl[1792 + tid];
            size_t grow = (size_t)z * S + tm * 256 + tid;
            Part[(size_t)tn * (BB * S) + grow] = make_float2(s, sq);
        }
    }
}

// ------- LayerNorm: partials + y(bf16) -> out(f32), one block per row -------
__global__ __launch_bounds__(256) void ln2(const unsigned short* __restrict__ ybf,
                                           const float2* __restrict__ part,
                                           const int* __restrict__ role,
                                           const float* __restrict__ gamma,
                                           const float* __restrict__ beta,
                                           float* __restrict__ out) {
    int row = blockIdx.x;
    int z = row >> 11;                 // row / S
    int r = role[z];
    float s = 0.f, ss = 0.f;
#pragma unroll
    for (int nb = 0; nb < 8; nb++) {
        float2 p = part[(size_t)nb * (BB * S) + row];
        s += p.x; ss += p.y;
    }
    float mean = s * (1.0f / H);
    float var = ss * (1.0f / H) - mean * mean;
    float rstd = rsqrtf(var + 1e-5f);
    int t = threadIdx.x;
    ushort8 yv = ((const ushort8*)(ybf + (size_t)row * H))[t];
    const float4* gp = (const float4*)(gamma + (size_t)r * H);
    const float4* bp = (const float4*)(beta + (size_t)r * H);
    float4 g0 = gp[2 * t], g1 = gp[2 * t + 1];
    float4 b0 = bp[2 * t], b1 = bp[2 * t + 1];
    float yo[8];
#pragma unroll
    for (int e = 0; e < 8; e++)
        yo[e] = (__uint_as_float(((unsigned)yv[e]) << 16) - mean) * rstd;
    float4 r0, r1;
    r0.x = yo[0] * g0.x + b0.x; r0.y = yo[1] * g0.y + b0.y;
    r0.z = yo[2] * g0.z + b0.z; r0.w = yo[3] * g0.w + b0.w;
    r1.x = yo[4] * g1.x + b1.x; r1.y = yo[5] * g1.y + b1.y;
    r1.z = yo[6] * g1.z + b1.z; r1.w = yo[7] * g1.w + b1.w;
    float4* op = (float4*)(out + (size_t)row * H);
    op[2 * t] = r0;
    op[2 * t + 1] = r1;
}

extern "C" void kernel_launch(void* const* d_in, const int* in_sizes, int n_in,
                              void* d_out, int out_size, void* d_ws, size_t ws_size,
                              hipStream_t stream) {
    const int* role = (const int*)d_in[0];
    const float* hs = (const float*)d_in[1];
    const float* Wd = (const float*)d_in[2];
    const float* bd = (const float*)d_in[3];
    const float* Wu = (const float*)d_in[4];
    const float* bu = (const float*)d_in[5];
    const float* gamma = (const float*)d_in[6];
    const float* beta = (const float*)d_in[7];
    float* out = (float*)d_out;

    char* ws = (char*)d_ws;
    // region A (64 MiB @0): hs_bf (cvt -> G1, resid of G2), then y_bf (G2 -> LN, in place)
    unsigned short* hs_bf = (unsigned short*)ws;
    unsigned short* y_bf = (unsigned short*)ws;
    // region B (12 MiB @64Mi): wd_t (tpose -> G1), then partials (G2 -> LN)
    unsigned short* wd_t = (unsigned short*)(ws + 67108864);
    float2* part = (float2*)(ws + 67108864);
    // region C (12 MiB @76Mi): wu_t
    unsigned short* wu_t = (unsigned short*)(ws + 67108864 + 12582912);
    // region D (32 MiB @88Mi): h
    unsigned short* h_ws = (unsigned short*)(ws + 67108864 + 2 * 12582912);

    cvt_hs<<<4096, 256, 0, stream>>>(hs, hs_bf, (BB * S * H) / 8);
    dim3 tb(32, 8);
    tpose<<<dim3(K / 32, H / 32, R), tb, 0, stream>>>(Wd, wd_t, H, K);
    tpose<<<dim3(H / 32, K / 32, R), tb, 0, stream>>>(Wu, wu_t, K, H);
    // GEMM1: h = gelu(hs_bf x Wd^T + bd), bf16; 256 blocks
    gemm_8ph<H, 0><<<(K / 256) * 8 * BB, 512, 0, stream>>>(hs_bf, wd_t, role, bd,
                                                           nullptr, h_ws, nullptr, K);
    // GEMM2: y = h x Wu^T + bu + hs_bf, bf16 in place + partial stats; 512 blocks
    gemm_8ph<K, 1><<<(H / 256) * 8 * BB, 512, 0, stream>>>(h_ws, wu_t, role, bu,
                                                           hs_bf, y_bf, part, H);
    ln2<<<BB * S, 256, 0, stream>>>(y_bf, part, role, gamma, beta, out);
}

// Round 7
// 255.958 us; speedup vs baseline: 1.2984x; 1.0024x over previous
//
#include <hip/hip_runtime.h>
#include <hip/hip_bf16.h>

#define H 2048
#define K 1024
#define R 3
#define BB 8
#define S 2048

typedef __bf16 bf16x8 __attribute__((ext_vector_type(8)));
typedef float f32x4 __attribute__((ext_vector_type(4)));
typedef unsigned short ushort8 __attribute__((ext_vector_type(8)));

static __device__ __forceinline__ unsigned short f2bf(float f) {
    unsigned int u = __float_as_uint(f);
    u += 0x7FFFu + ((u >> 16) & 1u);   // round-to-nearest-even
    return (unsigned short)(u >> 16);
}

#define GLOAD_LDS16(g, l)                                                      \
    __builtin_amdgcn_global_load_lds(                                          \
        (const __attribute__((address_space(1))) void*)(g),                    \
        (__attribute__((address_space(3))) void*)(l), 16, 0, 0)

// ---------------- convert hidden f32 -> bf16 ----------------
__global__ __launch_bounds__(256) void cvt_hs(const float* __restrict__ in,
                                              unsigned short* __restrict__ out,
                                              int n8) {
    int stride = gridDim.x * blockDim.x;
    for (int i = blockIdx.x * blockDim.x + threadIdx.x; i < n8; i += stride) {
        const float4* p = (const float4*)(in + (size_t)i * 8);
        float4 a = p[0], b = p[1];
        union { unsigned short us[8]; ushort8 v; } o;
        o.us[0] = f2bf(a.x); o.us[1] = f2bf(a.y);
        o.us[2] = f2bf(a.z); o.us[3] = f2bf(a.w);
        o.us[4] = f2bf(b.x); o.us[5] = f2bf(b.y);
        o.us[6] = f2bf(b.z); o.us[7] = f2bf(b.w);
        *(ushort8*)(out + (size_t)i * 8) = o.v;
    }
}

// -------- transpose+convert: in f32 [rows][cols] -> out bf16 [cols][rows] ----
__global__ __launch_bounds__(256) void tpose(const float* __restrict__ in,
                                             unsigned short* __restrict__ out,
                                             int rows, int cols) {
    __shared__ float tile[32][33];
    int rr = blockIdx.z;
    const float* ip = in + (size_t)rr * rows * cols;
    unsigned short* op = out + (size_t)rr * rows * cols;
    int x = blockIdx.x * 32 + threadIdx.x;
    int y0 = blockIdx.y * 32 + threadIdx.y;
#pragma unroll
    for (int j = 0; j < 32; j += 8)
        tile[threadIdx.y + j][threadIdx.x] = ip[(size_t)(y0 + j) * cols + x];
    __syncthreads();
    int ox = blockIdx.y * 32 + threadIdx.x;
    int oy0 = blockIdx.x * 32 + threadIdx.y;
#pragma unroll
    for (int j = 0; j < 32; j += 8)
        op[(size_t)(oy0 + j) * rows + ox] = f2bf(tile[threadIdx.x][threadIdx.y + j]);
}

// ======= 256x256 8-phase NT GEMM, BK=64, dbuf-2, COMPILE-TIME slot bases =====
// LDS 128 KiB: slot s (literal 0 / 65536): A at s+0 (256r x 128B), B at s+32768.
// Tile t -> slot0, t+1 -> slot1 (fixed per phase -> all ds_read/stage bases are
// compile-time; reads fold to base-VGPR + offset:imm; no sched_barrier (m141)).
// Stage plan / iter (2 loads per STAGE): P1: A(t+1)h0->s1  P2: A(t+1)h1->s1
//   P3: B(t+2)h0->s0  P4: B(t+2)h1->s0 + gate  P5: A(t+2)h0->s0
//   P6: A(t+2)h1->s0  P7: B(t+3)h0->s1  P8: B(t+3)h1->s1 + gate
// Gates vmcnt(4): at P4 outstanding = B(t+1)lo(4)+A(t+1)(4)+B(t+2)(4) = 12;
// forces B(t+1),A(t+1) (needed P5), leaves B(t+2). At P8 = B(t+2)+A(t+2)+
// B(t+3) = 12; forces B(t+2),A(t+2) (needed next P1), leaves B(t+3).
// WAR: every stage target's last reader drained (per-phase lgkmcnt(0)) >= 1
// barrier before the stage issues. Tail: vmcnt(0) when nothing newer needed.
// EPI 0: out = bf16 gelu(acc+bias) -> h
// EPI 1: out = bf16 (acc+bias+resid_bf16) IN PLACE over resid; row stats->Part
template <int KC, int EPI>
__global__ __launch_bounds__(512, 2) void gemm_8ph(
    const unsigned short* __restrict__ A, const unsigned short* __restrict__ Bt,
    const int* __restrict__ role, const float* __restrict__ bias,
    const unsigned short* __restrict__ resid, void* __restrict__ Out,
    float2* __restrict__ Part, int N) {
    constexpr int NT = KC / 64;          // even for all our KC
    __shared__ char smem[131072];
    const int tid = threadIdx.x;
    const int wid = tid >> 6, lane = tid & 63;
    const int wm = wid >> 2, wn = wid & 3;
    const int lr = lane & 15, lc = lane >> 4;

    const int nx = N >> 8;
    const int cpx = gridDim.x >> 3;
    const int orig = (blockIdx.x & 7) * cpx + (blockIdx.x >> 3);
    const int tn = orig % nx;
    const int tmz = orig / nx;
    const int tm = tmz & 7;              // S/256 = 8 m-tiles
    const int z = tmz >> 3;
    const int r = role[z];

    const char* Ab = (const char*)(A + ((size_t)z * S + (size_t)tm * 256) * KC);
    const char* Bb = (const char*)(Bt + ((size_t)r * N + (size_t)tn * 256) * KC);

    const int P16 = tid * 16;

    // stage ONE half-tile (128 rows x 128B) = 2 x global_load_lds(16B)
    // ldsoff must be a compile-time literal expression.
#define STAGE16(gbase, ldsoff, kt, half)                                       \
    do {                                                                       \
        _Pragma("unroll") for (int c_ = 0; c_ < 2; c_++) {                     \
            int P_ = c_ * 8192 + P16;                                          \
            int L_ = P_ ^ (((P_ >> 7) & 7) << 4);                              \
            const char* g_ = (gbase) +                                         \
                (size_t)((half) * 128 + (L_ >> 7)) * (KC * 2) +                \
                (size_t)(kt) * 128 + (L_ & 127);                               \
            GLOAD_LDS16(g_, smem + (ldsoff) + (half) * 16384 + P_);            \
        }                                                                      \
    } while (0)

    // prologue: A(0)->s0, B(0)->s0, B(1)->s1; force A(0),B(0); leave B(1) flying
    STAGE16(Ab, 0, 0, 0);        STAGE16(Ab, 0, 0, 1);
    STAGE16(Bb, 32768, 0, 0);    STAGE16(Bb, 32768, 0, 1);
    STAGE16(Bb, 98304, 1, 0);    STAGE16(Bb, 98304, 1, 1);
    asm volatile("s_waitcnt vmcnt(4)" ::: "memory");
    __builtin_amdgcn_s_barrier();

    f32x4 acc[8][4] = {};
    const int swz = (lr & 7) << 4;
    const int ck0 = (lc << 4) ^ swz;
    const int ck1 = ck0 ^ 0x40;
    const char* sm = smem;

#define LDA4(ibase, SL)                                                        \
    _Pragma("unroll") for (int i_ = 0; i_ < 4; i_++) {                         \
        int rb_ = (wm * 128 + ((ibase) + i_) * 16 + lr) << 7;                  \
        a[i_][0] = *(const bf16x8*)(sm + (SL) + rb_ + ck0);                    \
        a[i_][1] = *(const bf16x8*)(sm + (SL) + rb_ + ck1); }
#define LDB2(jbase, SL)                                                        \
    _Pragma("unroll") for (int j_ = 0; j_ < 2; j_++) {                         \
        int rb_ = (wn * 64 + ((jbase) + j_) * 16 + lr) << 7;                   \
        b[(jbase) + j_][0] = *(const bf16x8*)(sm + (SL) + 32768 + rb_ + ck0);  \
        b[(jbase) + j_][1] = *(const bf16x8*)(sm + (SL) + 32768 + rb_ + ck1); }
#define MFMA16(IOFF, JOFF)                                                     \
    _Pragma("unroll") for (int kk = 0; kk < 2; kk++)                           \
    _Pragma("unroll") for (int i_ = 0; i_ < 4; i_++)                           \
    _Pragma("unroll") for (int j_ = 0; j_ < 2; j_++)                           \
        acc[(IOFF) + i_][(JOFF) + j_] = __builtin_amdgcn_mfma_f32_16x16x32_bf16( \
            a[i_][kk], b[(JOFF) + j_][kk], acc[(IOFF) + i_][(JOFF) + j_], 0, 0, 0);
#define PH_MID()                                                               \
    __builtin_amdgcn_s_barrier();                                              \
    asm volatile("s_waitcnt lgkmcnt(0)" ::: "memory");                         \
    __builtin_amdgcn_s_setprio(1);
#define PH_END()                                                               \
    __builtin_amdgcn_s_setprio(0);                                             \
    __builtin_amdgcn_s_barrier();

#pragma unroll 1
    for (int t = 0; t < NT; t += 2) {
        bf16x8 a[4][2], b[4][2];
        const bool pf2 = (t + 2) < NT, pf3 = (t + 3) < NT;
        // ---- P1: compute (t, i0-3, j0-1) from slot0 ----
        LDA4(0, 0); LDB2(0, 0);
        STAGE16(Ab, 65536, t + 1, 0);
        asm volatile("s_waitcnt lgkmcnt(8)" ::: "memory");
        PH_MID(); MFMA16(0, 0); PH_END();
        // ---- P2: (t, i0-3, j2-3) ----
        LDB2(2, 0);
        STAGE16(Ab, 65536, t + 1, 1);
        PH_MID(); MFMA16(0, 2); PH_END();
        // ---- P3: (t, i4-7, j0-1) ----
        LDA4(4, 0);
        if (pf2) STAGE16(Bb, 32768, t + 2, 0);
        PH_MID(); MFMA16(4, 0); PH_END();
        // ---- P4: (t, i4-7, j2-3) + gate ----
        if (pf2) STAGE16(Bb, 32768, t + 2, 1);
        PH_MID(); MFMA16(4, 2);
        __builtin_amdgcn_s_setprio(0);
        if (pf2) asm volatile("s_waitcnt vmcnt(4)" ::: "memory");
        else     asm volatile("s_waitcnt vmcnt(0)" ::: "memory");
        __builtin_amdgcn_s_barrier();
        // ---- P5: compute (t+1, i0-3, j0-1) from slot1 ----
        LDA4(0, 65536); LDB2(0, 65536);
        if (pf2) STAGE16(Ab, 0, t + 2, 0);
        asm volatile("s_waitcnt lgkmcnt(8)" ::: "memory");
        PH_MID(); MFMA16(0, 0); PH_END();
        // ---- P6: (t+1, i0-3, j2-3) ----
        LDB2(2, 65536);
        if (pf2) STAGE16(Ab, 0, t + 2, 1);
        PH_MID(); MFMA16(0, 2); PH_END();
        // ---- P7: (t+1, i4-7, j0-1) ----
        LDA4(4, 65536);
        if (pf3) STAGE16(Bb, 98304, t + 3, 0);
        PH_MID(); MFMA16(4, 0); PH_END();
        // ---- P8: (t+1, i4-7, j2-3) + gate ----
        if (pf3) STAGE16(Bb, 98304, t + 3, 1);
        PH_MID(); MFMA16(4, 2);
        __builtin_amdgcn_s_setprio(0);
        if (pf2) {
            if (pf3) asm volatile("s_waitcnt vmcnt(4)" ::: "memory");
            else     asm volatile("s_waitcnt vmcnt(0)" ::: "memory");
            __builtin_amdgcn_s_barrier();
        }
    }
#undef STAGE16
#undef LDA4
#undef LDB2
#undef MFMA16
#undef PH_MID
#undef PH_END

    // ---- epilogue ----
    const int base_m = tm * 256 + wm * 128;
    const int base_n = tn * 256 + wn * 64;
    float bn[4];
    const float* bp = bias + (size_t)r * N + base_n;
#pragma unroll
    for (int j = 0; j < 4; j++) bn[j] = bp[j * 16 + lr];

    if (EPI == 0) {
        unsigned short* o = (unsigned short*)Out;
#pragma unroll
        for (int i = 0; i < 8; i++) {
#pragma unroll
            for (int j = 0; j < 4; j++) {
#pragma unroll
                for (int q = 0; q < 4; q++) {
                    size_t grow = (size_t)z * S + base_m + i * 16 + lc * 4 + q;
                    int col = base_n + j * 16 + lr;
                    float x = acc[i][j][q] + bn[j];
                    float g = 0.5f * x * (1.0f + erff(x * 0.70710678118654752f));
                    o[grow * N + col] = f2bf(g);
                }
            }
        }
    } else {
        unsigned short* o = (unsigned short*)Out;     // y bf16 (in place on resid)
        float* pl = (float*)smem;                     // [8][256] partials
        __syncthreads();
#pragma unroll
        for (int i = 0; i < 8; i++) {
#pragma unroll
            for (int q = 0; q < 4; q++) {
                size_t grow = (size_t)z * S + base_m + i * 16 + lc * 4 + q;
                float s = 0.f, sq = 0.f;
#pragma unroll
                for (int j = 0; j < 4; j++) {
                    int col = base_n + j * 16 + lr;
                    float rv = __uint_as_float(((unsigned)resid[grow * (size_t)N + col]) << 16);
                    float y = acc[i][j][q] + bn[j] + rv;
                    o[grow * (size_t)N + col] = f2bf(y);
                    s += y; sq += y * y;
                }
#pragma unroll
                for (int off = 1; off < 16; off <<= 1) {
                    s  += __shfl_xor(s, off);
                    sq += __shfl_xor(sq, off);
                }
                if (lr == 0) {
                    int rloc = wm * 128 + i * 16 + lc * 4 + q;
                    pl[wn * 256 + rloc] = s;
                    pl[(4 + wn) * 256 + rloc] = sq;
                }
            }
        }
        __syncthreads();
        if (tid < 256) {
            float s  = pl[tid] + pl[256 + tid] + pl[512 + tid] + pl[768 + tid];
            float sq = pl[1024 + tid] + pl[1280 + tid] + pl[1536 + tid] + pl[1792 + tid];
            size_t grow = (size_t)z * S + tm * 256 + tid;
            Part[(size_t)tn * (BB * S) + grow] = make_float2(s, sq);
        }
    }
}

// ------- LayerNorm: partials + y(bf16) -> out(f32), one block per row -------
__global__ __launch_bounds__(256) void ln2(const unsigned short* __restrict__ ybf,
                                           const float2* __restrict__ part,
                                           const int* __restrict__ role,
                                           const float* __restrict__ gamma,
                                           const float* __restrict__ beta,
                                           float* __restrict__ out) {
    int row = blockIdx.x;
    int z = row >> 11;                 // row / S
    int r = role[z];
    float s = 0.f, ss = 0.f;
#pragma unroll
    for (int nb = 0; nb < 8; nb++) {
        float2 p = part[(size_t)nb * (BB * S) + row];
        s += p.x; ss += p.y;
    }
    float mean = s * (1.0f / H);
    float var = ss * (1.0f / H) - mean * mean;
    float rstd = rsqrtf(var + 1e-5f);
    int t = threadIdx.x;
    ushort8 yv = ((const ushort8*)(ybf + (size_t)row * H))[t];
    const float4* gp = (const float4*)(gamma + (size_t)r * H);
    const float4* bp = (const float4*)(beta + (size_t)r * H);
    float4 g0 = gp[2 * t], g1 = gp[2 * t + 1];
    float4 b0 = bp[2 * t], b1 = bp[2 * t + 1];
    float yo[8];
#pragma unroll
    for (int e = 0; e < 8; e++)
        yo[e] = (__uint_as_float(((unsigned)yv[e]) << 16) - mean) * rstd;
    float4 r0, r1;
    r0.x = yo[0] * g0.x + b0.x; r0.y = yo[1] * g0.y + b0.y;
    r0.z = yo[2] * g0.z + b0.z; r0.w = yo[3] * g0.w + b0.w;
    r1.x = yo[4] * g1.x + b1.x; r1.y = yo[5] * g1.y + b1.y;
    r1.z = yo[6] * g1.z + b1.z; r1.w = yo[7] * g1.w + b1.w;
    float4* op = (float4*)(out + (size_t)row * H);
    op[2 * t] = r0;
    op[2 * t + 1] = r1;
}

extern "C" void kernel_launch(void* const* d_in, const int* in_sizes, int n_in,
                              void* d_out, int out_size, void* d_ws, size_t ws_size,
                              hipStream_t stream) {
    const int* role = (const int*)d_in[0];
    const float* hs = (const float*)d_in[1];
    const float* Wd = (const float*)d_in[2];
    const float* bd = (const float*)d_in[3];
    const float* Wu = (const float*)d_in[4];
    const float* bu = (const float*)d_in[5];
    const float* gamma = (const float*)d_in[6];
    const float* beta = (const float*)d_in[7];
    float* out = (float*)d_out;

    char* ws = (char*)d_ws;
    // region A (64 MiB @0): hs_bf (cvt -> G1, resid of G2), then y_bf (G2 -> LN, in place)
    unsigned short* hs_bf = (unsigned short*)ws;
    unsigned short* y_bf = (unsigned short*)ws;
    // region B (12 MiB @64Mi): wd_t (tpose -> G1), then partials (G2 -> LN)
    unsigned short* wd_t = (unsigned short*)(ws + 67108864);
    float2* part = (float2*)(ws + 67108864);
    // region C (12 MiB @76Mi): wu_t
    unsigned short* wu_t = (unsigned short*)(ws + 67108864 + 12582912);
    // region D (32 MiB @88Mi): h
    unsigned short* h_ws = (unsigned short*)(ws + 67108864 + 2 * 12582912);

    cvt_hs<<<4096, 256, 0, stream>>>(hs, hs_bf, (BB * S * H) / 8);
    dim3 tb(32, 8);
    tpose<<<dim3(K / 32, H / 32, R), tb, 0, stream>>>(Wd, wd_t, H, K);
    tpose<<<dim3(H / 32, K / 32, R), tb, 0, stream>>>(Wu, wu_t, K, H);
    // GEMM1: h = gelu(hs_bf x Wd^T + bd), bf16; 256 blocks
    gemm_8ph<H, 0><<<(K / 256) * 8 * BB, 512, 0, stream>>>(hs_bf, wd_t, role, bd,
                                                           nullptr, h_ws, nullptr, K);
    // GEMM2: y = h x Wu^T + bu + hs_bf, bf16 in place + partial stats; 512 blocks
    gemm_8ph<K, 1><<<(H / 256) * 8 * BB, 512, 0, stream>>>(h_ws, wu_t, role, bu,
                                                           hs_bf, y_bf, part, H);
    ln2<<<BB * S, 256, 0, stream>>>(y_bf, part, role, gamma, beta, out);
}

// Round 8
// 252.972 us; speedup vs baseline: 1.3138x; 1.0118x over previous
//
#include <hip/hip_runtime.h>
#include <hip/hip_bf16.h>

#define H 2048
#define K 1024
#define R 3
#define BB 8
#define S 2048

typedef __bf16 bf16x8 __attribute__((ext_vector_type(8)));
typedef float f32x4 __attribute__((ext_vector_type(4)));
typedef unsigned short ushort8 __attribute__((ext_vector_type(8)));

static __device__ __forceinline__ unsigned short f2bf(float f) {
    unsigned int u = __float_as_uint(f);
    u += 0x7FFFu + ((u >> 16) & 1u);   // round-to-nearest-even
    return (unsigned short)(u >> 16);
}

#define GLOAD_LDS16(g, l)                                                      \
    __builtin_amdgcn_global_load_lds(                                          \
        (const __attribute__((address_space(1))) void*)(g),                    \
        (__attribute__((address_space(3))) void*)(l), 16, 0, 0)

// ---------------- convert hidden f32 -> bf16 ----------------
__global__ __launch_bounds__(256) void cvt_hs(const float* __restrict__ in,
                                              unsigned short* __restrict__ out,
                                              int n8) {
    int stride = gridDim.x * blockDim.x;
    for (int i = blockIdx.x * blockDim.x + threadIdx.x; i < n8; i += stride) {
        const float4* p = (const float4*)(in + (size_t)i * 8);
        float4 a = p[0], b = p[1];
        union { unsigned short us[8]; ushort8 v; } o;
        o.us[0] = f2bf(a.x); o.us[1] = f2bf(a.y);
        o.us[2] = f2bf(a.z); o.us[3] = f2bf(a.w);
        o.us[4] = f2bf(b.x); o.us[5] = f2bf(b.y);
        o.us[6] = f2bf(b.z); o.us[7] = f2bf(b.w);
        *(ushort8*)(out + (size_t)i * 8) = o.v;
    }
}

// -------- transpose+convert: in f32 [rows][cols] -> out bf16 [cols][rows] ----
__global__ __launch_bounds__(256) void tpose(const float* __restrict__ in,
                                             unsigned short* __restrict__ out,
                                             int rows, int cols) {
    __shared__ float tile[32][33];
    int rr = blockIdx.z;
    const float* ip = in + (size_t)rr * rows * cols;
    unsigned short* op = out + (size_t)rr * rows * cols;
    int x = blockIdx.x * 32 + threadIdx.x;
    int y0 = blockIdx.y * 32 + threadIdx.y;
#pragma unroll
    for (int j = 0; j < 32; j += 8)
        tile[threadIdx.y + j][threadIdx.x] = ip[(size_t)(y0 + j) * cols + x];
    __syncthreads();
    int ox = blockIdx.y * 32 + threadIdx.x;
    int oy0 = blockIdx.x * 32 + threadIdx.y;
#pragma unroll
    for (int j = 0; j < 32; j += 8)
        op[(size_t)(oy0 + j) * rows + ox] = f2bf(tile[threadIdx.x][threadIdx.y + j]);
}

// ==== 256x256 8-phase NT GEMM, BK=64, dbuf-2, ONE barrier per phase ====
// Phase = {ds_reads (compiler-visible); STAGE; setprio(1); 16 MFMA;
// setprio(0); s_barrier}. No explicit lgkmcnt: the backend emits fine-grained
// per-wave lgkmcnt before each MFMA group, so one wave's MFMA overlaps other
// waves' LDS drain (the lockstep lgkmcnt(0)+double-barrier of the previous
// version serialized LDS and MFMA CU-wide -> 29% MfmaUtil ceiling).
// Stage plan / iter: P1: A(t+1)h0->s1  P2: A(t+1)h1->s1  P3: B(t+2)h0->s0
//   P4: B(t+2)h1->s0 +gate  P5: A(t+2)h0->s0  P6: A(t+2)h1->s0
//   P7: B(t+3)h0->s1  P8: B(t+3)h1->s1 +gate
// Gates vmcnt(4): at P4 outstanding<=12, forces B(t+1),A(t+1) (needed P5);
// at P8 forces B(t+2),A(t+2) (needed next P1). Barriers carry "memory" so
// reads cannot hoist above a gate. WAR: each stage target's last readers
// consumed their data pre-barrier >=1 phase earlier.
// EPI 0: out = bf16 gelu(acc+bias) -> h
// EPI 1: out = bf16 (acc+bias+resid_bf16) IN PLACE over resid; row stats->Part
template <int KC, int EPI>
__global__ __launch_bounds__(512, 2) void gemm_8ph(
    const unsigned short* __restrict__ A, const unsigned short* __restrict__ Bt,
    const int* __restrict__ role, const float* __restrict__ bias,
    const unsigned short* __restrict__ resid, void* __restrict__ Out,
    float2* __restrict__ Part, int N) {
    constexpr int NT = KC / 64;          // even for all our KC
    __shared__ char smem[131072];
    const int tid = threadIdx.x;
    const int wid = tid >> 6, lane = tid & 63;
    const int wm = wid >> 2, wn = wid & 3;
    const int lr = lane & 15, lc = lane >> 4;

    const int nx = N >> 8;
    const int cpx = gridDim.x >> 3;
    const int orig = (blockIdx.x & 7) * cpx + (blockIdx.x >> 3);
    const int tn = orig % nx;
    const int tmz = orig / nx;
    const int tm = tmz & 7;              // S/256 = 8 m-tiles
    const int z = tmz >> 3;
    const int r = role[z];

    const char* Ab = (const char*)(A + ((size_t)z * S + (size_t)tm * 256) * KC);
    const char* Bb = (const char*)(Bt + ((size_t)r * N + (size_t)tn * 256) * KC);

    const int P16 = tid * 16;

    // stage ONE half-tile (128 rows x 128B) = 2 x global_load_lds(16B)
#define STAGE16(gbase, ldsoff, kt, half)                                       \
    do {                                                                       \
        _Pragma("unroll") for (int c_ = 0; c_ < 2; c_++) {                     \
            int P_ = c_ * 8192 + P16;                                          \
            int L_ = P_ ^ (((P_ >> 7) & 7) << 4);                              \
            const char* g_ = (gbase) +                                         \
                (size_t)((half) * 128 + (L_ >> 7)) * (KC * 2) +                \
                (size_t)(kt) * 128 + (L_ & 127);                               \
            GLOAD_LDS16(g_, smem + (ldsoff) + (half) * 16384 + P_);            \
        }                                                                      \
    } while (0)

    // prologue: A(0)->s0, B(0)->s0, B(1)->s1; force A(0),B(0); leave B(1) flying
    STAGE16(Ab, 0, 0, 0);        STAGE16(Ab, 0, 0, 1);
    STAGE16(Bb, 32768, 0, 0);    STAGE16(Bb, 32768, 0, 1);
    STAGE16(Bb, 98304, 1, 0);    STAGE16(Bb, 98304, 1, 1);
    asm volatile("s_waitcnt vmcnt(4)" ::: "memory");
    __builtin_amdgcn_s_barrier();

    f32x4 acc[8][4] = {};
    const int swz = (lr & 7) << 4;
    const int ck0 = (lc << 4) ^ swz;
    const int ck1 = ck0 ^ 0x40;
    const char* sm = smem;

#define LDA4(ibase, SL)                                                        \
    _Pragma("unroll") for (int i_ = 0; i_ < 4; i_++) {                         \
        int rb_ = (wm * 128 + ((ibase) + i_) * 16 + lr) << 7;                  \
        a[i_][0] = *(const bf16x8*)(sm + (SL) + rb_ + ck0);                    \
        a[i_][1] = *(const bf16x8*)(sm + (SL) + rb_ + ck1); }
#define LDB2(jbase, SL)                                                        \
    _Pragma("unroll") for (int j_ = 0; j_ < 2; j_++) {                         \
        int rb_ = (wn * 64 + ((jbase) + j_) * 16 + lr) << 7;                   \
        b[(jbase) + j_][0] = *(const bf16x8*)(sm + (SL) + 32768 + rb_ + ck0);  \
        b[(jbase) + j_][1] = *(const bf16x8*)(sm + (SL) + 32768 + rb_ + ck1); }
#define MFMA16(IOFF, JOFF)                                                     \
    _Pragma("unroll") for (int kk = 0; kk < 2; kk++)                           \
    _Pragma("unroll") for (int i_ = 0; i_ < 4; i_++)                           \
    _Pragma("unroll") for (int j_ = 0; j_ < 2; j_++)                           \
        acc[(IOFF) + i_][(JOFF) + j_] = __builtin_amdgcn_mfma_f32_16x16x32_bf16( \
            a[i_][kk], b[(JOFF) + j_][kk], acc[(IOFF) + i_][(JOFF) + j_], 0, 0, 0);
#define PH_CUT()                                                               \
    __builtin_amdgcn_s_setprio(0);                                             \
    asm volatile("s_barrier" ::: "memory");

#pragma unroll 1
    for (int t = 0; t < NT; t += 2) {
        bf16x8 a[4][2], b[4][2];
        const bool pf2 = (t + 2) < NT, pf3 = (t + 3) < NT;
        // ---- P1: compute (t, i0-3, j0-1) from slot0 ----
        LDA4(0, 0); LDB2(0, 0);
        STAGE16(Ab, 65536, t + 1, 0);
        __builtin_amdgcn_s_setprio(1);
        MFMA16(0, 0);
        PH_CUT();
        // ---- P2: (t, i0-3, j2-3) ----
        LDB2(2, 0);
        STAGE16(Ab, 65536, t + 1, 1);
        __builtin_amdgcn_s_setprio(1);
        MFMA16(0, 2);
        PH_CUT();
        // ---- P3: (t, i4-7, j0-1) ----
        LDA4(4, 0);
        if (pf2) STAGE16(Bb, 32768, t + 2, 0);
        __builtin_amdgcn_s_setprio(1);
        MFMA16(4, 0);
        PH_CUT();
        // ---- P4: (t, i4-7, j2-3) + gate ----
        if (pf2) STAGE16(Bb, 32768, t + 2, 1);
        __builtin_amdgcn_s_setprio(1);
        MFMA16(4, 2);
        __builtin_amdgcn_s_setprio(0);
        if (pf2) asm volatile("s_waitcnt vmcnt(4)" ::: "memory");
        else     asm volatile("s_waitcnt vmcnt(0)" ::: "memory");
        asm volatile("s_barrier" ::: "memory");
        // ---- P5: compute (t+1, i0-3, j0-1) from slot1 ----
        LDA4(0, 65536); LDB2(0, 65536);
        if (pf2) STAGE16(Ab, 0, t + 2, 0);
        __builtin_amdgcn_s_setprio(1);
        MFMA16(0, 0);
        PH_CUT();
        // ---- P6: (t+1, i0-3, j2-3) ----
        LDB2(2, 65536);
        if (pf2) STAGE16(Ab, 0, t + 2, 1);
        __builtin_amdgcn_s_setprio(1);
        MFMA16(0, 2);
        PH_CUT();
        // ---- P7: (t+1, i4-7, j0-1) ----
        LDA4(4, 65536);
        if (pf3) STAGE16(Bb, 98304, t + 3, 0);
        __builtin_amdgcn_s_setprio(1);
        MFMA16(4, 0);
        PH_CUT();
        // ---- P8: (t+1, i4-7, j2-3) + gate ----
        if (pf3) STAGE16(Bb, 98304, t + 3, 1);
        __builtin_amdgcn_s_setprio(1);
        MFMA16(4, 2);
        __builtin_amdgcn_s_setprio(0);
        if (pf2) {
            if (pf3) asm volatile("s_waitcnt vmcnt(4)" ::: "memory");
            else     asm volatile("s_waitcnt vmcnt(0)" ::: "memory");
            asm volatile("s_barrier" ::: "memory");
        }
    }
#undef STAGE16
#undef LDA4
#undef LDB2
#undef MFMA16
#undef PH_CUT

    // ---- epilogue ----
    const int base_m = tm * 256 + wm * 128;
    const int base_n = tn * 256 + wn * 64;
    float bn[4];
    const float* bp = bias + (size_t)r * N + base_n;
#pragma unroll
    for (int j = 0; j < 4; j++) bn[j] = bp[j * 16 + lr];

    if (EPI == 0) {
        unsigned short* o = (unsigned short*)Out;
#pragma unroll
        for (int i = 0; i < 8; i++) {
#pragma unroll
            for (int j = 0; j < 4; j++) {
#pragma unroll
                for (int q = 0; q < 4; q++) {
                    size_t grow = (size_t)z * S + base_m + i * 16 + lc * 4 + q;
                    int col = base_n + j * 16 + lr;
                    float x = acc[i][j][q] + bn[j];
                    float g = 0.5f * x * (1.0f + erff(x * 0.70710678118654752f));
                    o[grow * N + col] = f2bf(g);
                }
            }
        }
    } else {
        unsigned short* o = (unsigned short*)Out;     // y bf16 (in place on resid)
        float* pl = (float*)smem;                     // [8][256] partials
        __syncthreads();
#pragma unroll
        for (int i = 0; i < 8; i++) {
#pragma unroll
            for (int q = 0; q < 4; q++) {
                size_t grow = (size_t)z * S + base_m + i * 16 + lc * 4 + q;
                float s = 0.f, sq = 0.f;
#pragma unroll
                for (int j = 0; j < 4; j++) {
                    int col = base_n + j * 16 + lr;
                    float rv = __uint_as_float(((unsigned)resid[grow * (size_t)N + col]) << 16);
                    float y = acc[i][j][q] + bn[j] + rv;
                    o[grow * (size_t)N + col] = f2bf(y);
                    s += y; sq += y * y;
                }
#pragma unroll
                for (int off = 1; off < 16; off <<= 1) {
                    s  += __shfl_xor(s, off);
                    sq += __shfl_xor(sq, off);
                }
                if (lr == 0) {
                    int rloc = wm * 128 + i * 16 + lc * 4 + q;
                    pl[wn * 256 + rloc] = s;
                    pl[(4 + wn) * 256 + rloc] = sq;
                }
            }
        }
        __syncthreads();
        if (tid < 256) {
            float s  = pl[tid] + pl[256 + tid] + pl[512 + tid] + pl[768 + tid];
            float sq = pl[1024 + tid] + pl[1280 + tid] + pl[1536 + tid] + pl[1792 + tid];
            size_t grow = (size_t)z * S + tm * 256 + tid;
            Part[(size_t)tn * (BB * S) + grow] = make_float2(s, sq);
        }
    }
}

// ------- LayerNorm: partials + y(bf16) -> out(f32), one block per row -------
__global__ __launch_bounds__(256) void ln2(const unsigned short* __restrict__ ybf,
                                           const float2* __restrict__ part,
                                           const int* __restrict__ role,
                                           const float* __restrict__ gamma,
                                           const float* __restrict__ beta,
                                           float* __restrict__ out) {
    int row = blockIdx.x;
    int z = row >> 11;                 // row / S
    int r = role[z];
    float s = 0.f, ss = 0.f;
#pragma unroll
    for (int nb = 0; nb < 8; nb++) {
        float2 p = part[(size_t)nb * (BB * S) + row];
        s += p.x; ss += p.y;
    }
    float mean = s * (1.0f / H);
    float var = ss * (1.0f / H) - mean * mean;
    float rstd = rsqrtf(var + 1e-5f);
    int t = threadIdx.x;
    ushort8 yv = ((const ushort8*)(ybf + (size_t)row * H))[t];
    const float4* gp = (const float4*)(gamma + (size_t)r * H);
    const float4* bp = (const float4*)(beta + (size_t)r * H);
    float4 g0 = gp[2 * t], g1 = gp[2 * t + 1];
    float4 b0 = bp[2 * t], b1 = bp[2 * t + 1];
    float yo[8];
#pragma unroll
    for (int e = 0; e < 8; e++)
        yo[e] = (__uint_as_float(((unsigned)yv[e]) << 16) - mean) * rstd;
    float4 r0, r1;
    r0.x = yo[0] * g0.x + b0.x; r0.y = yo[1] * g0.y + b0.y;
    r0.z = yo[2] * g0.z + b0.z; r0.w = yo[3] * g0.w + b0.w;
    r1.x = yo[4] * g1.x + b1.x; r1.y = yo[5] * g1.y + b1.y;
    r1.z = yo[6] * g1.z + b1.z; r1.w = yo[7] * g1.w + b1.w;
    float4* op = (float4*)(out + (size_t)row * H);
    op[2 * t] = r0;
    op[2 * t + 1] = r1;
}

extern "C" void kernel_launch(void* const* d_in, const int* in_sizes, int n_in,
                              void* d_out, int out_size, void* d_ws, size_t ws_size,
                              hipStream_t stream) {
    const int* role = (const int*)d_in[0];
    const float* hs = (const float*)d_in[1];
    const float* Wd = (const float*)d_in[2];
    const float* bd = (const float*)d_in[3];
    const float* Wu = (const float*)d_in[4];
    const float* bu = (const float*)d_in[5];
    const float* gamma = (const float*)d_in[6];
    const float* beta = (const float*)d_in[7];
    float* out = (float*)d_out;

    char* ws = (char*)d_ws;
    // region A (64 MiB @0): hs_bf (cvt -> G1, resid of G2), then y_bf (G2 -> LN, in place)
    unsigned short* hs_bf = (unsigned short*)ws;
    unsigned short* y_bf = (unsigned short*)ws;
    // region B (12 MiB @64Mi): wd_t (tpose -> G1), then partials (G2 -> LN)
    unsigned short* wd_t = (unsigned short*)(ws + 67108864);
    float2* part = (float2*)(ws + 67108864);
    // region C (12 MiB @76Mi): wu_t
    unsigned short* wu_t = (unsigned short*)(ws + 67108864 + 12582912);
    // region D (32 MiB @88Mi): h
    unsigned short* h_ws = (unsigned short*)(ws + 67108864 + 2 * 12582912);

    cvt_hs<<<4096, 256, 0, stream>>>(hs, hs_bf, (BB * S * H) / 8);
    dim3 tb(32, 8);
    tpose<<<dim3(K / 32, H / 32, R), tb, 0, stream>>>(Wd, wd_t, H, K);
    tpose<<<dim3(H / 32, K / 32, R), tb, 0, stream>>>(Wu, wu_t, K, H);
    // GEMM1: h = gelu(hs_bf x Wd^T + bd), bf16; 256 blocks
    gemm_8ph<H, 0><<<(K / 256) * 8 * BB, 512, 0, stream>>>(hs_bf, wd_t, role, bd,
                                                           nullptr, h_ws, nullptr, K);
    // GEMM2: y = h x Wu^T + bu + hs_bf, bf16 in place + partial stats; 512 blocks
    gemm_8ph<K, 1><<<(H / 256) * 8 * BB, 512, 0, stream>>>(h_ws, wu_t, role, bu,
                                                           hs_bf, y_bf, part, H);
    ln2<<<BB * S, 256, 0, stream>>>(y_bf, part, role, gamma, beta, out);
}